// Round 1
// baseline (1480.741 us; speedup 1.0000x reference)
//
#include <hip/hip_runtime.h>
#include <math.h>

#define NB 4
#define NL 1024
#define NDIM 1024
#define NH 16
#define NDH 64
#define NEG_MAX (-3.402823466e38f)

// ---------------- silu(time) ----------------
__global__ __launch_bounds__(256) void k_silu(const float* __restrict__ t, float* __restrict__ o){
    int i = blockIdx.x*256 + threadIdx.x;            // NB*NDIM = 4096
    float v = t[i];
    o[i] = v / (1.f + __expf(-v));
}

// ---------------- ss = silu(time) @ Wt.T + bt  (one wave per output) ----------------
__global__ __launch_bounds__(256) void k_ss(const float* __restrict__ st, const float* __restrict__ Wt,
                                            const float* __restrict__ bt, float* __restrict__ ss){
    int gw   = (blockIdx.x*256 + threadIdx.x) >> 6;  // 0..8191
    int lane = threadIdx.x & 63;
    int b = gw >> 11, j = gw & 2047;
    const float* a = st + b*NDIM;
    const float* w = Wt + j*NDIM;
    float s = 0.f;
    #pragma unroll 4
    for (int i = lane; i < NDIM; i += 64) s += a[i]*w[i];
    #pragma unroll
    for (int off=32; off; off>>=1) s += __shfl_xor(s, off, 64);
    if (!lane) ss[gw] = s + bt[j];
}

// ---------------- counts[b][c] = sum_l (chain==c)*cyclic ----------------
__global__ __launch_bounds__(256) void k_counts(const int* __restrict__ chain, const float* __restrict__ cyc,
                                                float* __restrict__ counts){
    int b = blockIdx.x >> 1, c = blockIdx.x & 1;     // grid = 8
    float s = 0.f;
    for (int l = threadIdx.x; l < NL; l += 256)
        s += (chain[b*NL+l]==c) ? cyc[b*NL+l] : 0.f;
    __shared__ float red[4];
    #pragma unroll
    for (int off=32; off; off>>=1) s += __shfl_xor(s, off, 64);
    if (!(threadIdx.x & 63)) red[threadIdx.x>>6] = s;
    __syncthreads();
    if (!threadIdx.x) counts[blockIdx.x] = red[0]+red[1]+red[2]+red[3];
}

// ---------------- cos/sin angle tables [B,L,32] ----------------
__global__ __launch_bounds__(256) void k_angles(const int* __restrict__ resi, const int* __restrict__ chain,
                                                const float* __restrict__ cyc, const float* __restrict__ rf,
                                                const float* __restrict__ counts,
                                                float* __restrict__ cosb, float* __restrict__ sinb){
    int idx = blockIdx.x*256 + threadIdx.x;          // NB*NL*32 = 131072
    int f  = idx & 31;
    int bl = idx >> 5;
    int b  = bl >> 10;
    float t  = (float)resi[bl];
    int   ci = chain[bl];
    float cm = cyc[bl];
    float ang;
    if (cm > 0.f) {
        float ring      = counts[b*2+ci] * cm;
        float ring_safe = fmaxf(ring, 1.f);
        float max_k     = fmaxf(floorf(ring_safe*0.5f), 1.f);
        float k_eff     = (max_k == 1.f) ? 1.f : (1.f + fmodf((float)f, max_k));
        float omega     = 6.28318530717958647692f * k_eff / ring_safe;
        ang = omega * t;
    } else {
        ang = t * rf[f] + (float)ci * rf[0];
    }
    cosb[idx] = cosf(ang);
    sinb[idx] = sinf(ang);
}

// ---------------- layernorm + adaLN modulate -> xc ----------------
__global__ __launch_bounds__(256) void k_lnmod(const float* __restrict__ x, const float* __restrict__ sm,
                                               const float* __restrict__ gamma, const float* __restrict__ ss,
                                               float* __restrict__ xc){
    int row = blockIdx.x;                            // 0..4095
    int b   = row >> 10;
    int t   = threadIdx.x;
    float msk = sm[row];
    float4 v = ((const float4*)(x + (size_t)row*NDIM))[t];
    v.x*=msk; v.y*=msk; v.z*=msk; v.w*=msk;
    float s1 = v.x+v.y+v.z+v.w;
    float s2 = v.x*v.x + v.y*v.y + v.z*v.z + v.w*v.w;
    __shared__ float r1[4], r2[4];
    #pragma unroll
    for (int off=32; off; off>>=1){ s1 += __shfl_xor(s1,off,64); s2 += __shfl_xor(s2,off,64); }
    if (!(t & 63)){ r1[t>>6]=s1; r2[t>>6]=s2; }
    __syncthreads();
    s1 = r1[0]+r1[1]+r1[2]+r1[3];
    s2 = r2[0]+r2[1]+r2[2]+r2[3];
    float mu  = s1 * (1.f/NDIM);
    float var = s2 * (1.f/NDIM) - mu*mu;
    float rs  = rsqrtf(var + 1e-5f);
    const float* sc = ss + b*2048;
    float4 g   = ((const float4*)gamma)[t];
    float4 scl = ((const float4*)sc)[t];
    float4 sh  = ((const float4*)(sc+1024))[t];
    float4 o;
    o.x = (v.x-mu)*rs*g.x*(1.f+scl.x)+sh.x;
    o.y = (v.y-mu)*rs*g.y*(1.f+scl.y)+sh.y;
    o.z = (v.z-mu)*rs*g.z*(1.f+scl.z)+sh.z;
    o.w = (v.w-mu)*rs*g.w*(1.f+scl.w)+sh.w;
    ((float4*)(xc + (size_t)row*NDIM))[t] = o;
}

// ---------------- tiled f32 GEMM: out[m,n] = sum_k A[m,k]*W[n,k] ----------------
// MODE 1: write q [B,H,L,DH];  MODE 2: split kv -> k,v [B,H,L,DH];  MODE 3: out * seq_mask
template<int MODE>
__global__ __launch_bounds__(256) void k_gemm(const float* __restrict__ A, const float* __restrict__ W,
                                              float* __restrict__ out0, float* __restrict__ out1,
                                              const float* __restrict__ smask){
    __shared__ float As[64][17];
    __shared__ float Bs[64][17];
    int t  = threadIdx.x;
    int m0 = blockIdx.y*64, n0 = blockIdx.x*64;
    int lr = t>>2, lc = (t&3)*4;
    int tx = t&15, ty = t>>4;
    float acc[4][4] = {};
    for (int k0=0; k0<NDIM; k0+=16){
        float4 av = *(const float4*)(A + (size_t)(m0+lr)*NDIM + k0 + lc);
        float4 bv = *(const float4*)(W + (size_t)(n0+lr)*NDIM + k0 + lc);
        __syncthreads();
        As[lr][lc]=av.x; As[lr][lc+1]=av.y; As[lr][lc+2]=av.z; As[lr][lc+3]=av.w;
        Bs[lr][lc]=bv.x; Bs[lr][lc+1]=bv.y; Bs[lr][lc+2]=bv.z; Bs[lr][lc+3]=bv.w;
        __syncthreads();
        #pragma unroll
        for (int k=0;k<16;k++){
            float a[4], bb[4];
            #pragma unroll
            for (int i=0;i<4;i++) a[i]  = As[ty*4+i][k];
            #pragma unroll
            for (int j=0;j<4;j++) bb[j] = Bs[tx*4+j][k];
            #pragma unroll
            for (int i=0;i<4;i++)
                #pragma unroll
                for (int j=0;j<4;j++)
                    acc[i][j] += a[i]*bb[j];
        }
    }
    #pragma unroll
    for (int i=0;i<4;i++){
        int m = m0 + ty*4 + i;
        int b_ = m>>10, l_ = m&1023;
        float msk = (MODE==3) ? smask[m] : 0.f;
        #pragma unroll
        for (int j=0;j<4;j++){
            int n = n0 + tx*4 + j;
            if (MODE==1){
                int h_ = n>>6, d_ = n&63;
                out0[(size_t)((b_*NH + h_)*NL + l_)*NDH + d_] = acc[i][j];
            } else if (MODE==2){
                if (n < 1024){
                    int h_ = n>>6, d_ = n&63;
                    out0[(size_t)((b_*NH + h_)*NL + l_)*NDH + d_] = acc[i][j];
                } else {
                    int nn = n-1024, h_ = nn>>6, d_ = nn&63;
                    out1[(size_t)((b_*NH + h_)*NL + l_)*NDH + d_] = acc[i][j];
                }
            } else {
                out0[(size_t)m*NDIM + n] = acc[i][j]*msk;
            }
        }
    }
}

// ---------------- RoPE (interleaved pairs) on q and k ----------------
__global__ __launch_bounds__(256) void k_rope(float* __restrict__ q, float* __restrict__ k,
                                              const float* __restrict__ cosb, const float* __restrict__ sinb){
    int idx = blockIdx.x*256 + threadIdx.x;          // NB*NH*NL*32 = 2097152
    int f   = idx & 31;
    int bhl = idx >> 5;
    int l   = bhl & 1023;
    int b   = bhl >> 14;
    int ca  = ((b<<10)|l)*32 + f;
    float c = cosb[ca], s = sinb[ca];
    float2 qv = ((float2*)q)[idx];
    float2 kv = ((float2*)k)[idx];
    ((float2*)q)[idx] = make_float2(qv.x*c - qv.y*s, qv.y*c + qv.x*s);
    ((float2*)k)[idx] = make_float2(kv.x*c - kv.y*s, kv.y*c + kv.x*s);
}

// ---------------- flash attention, 1 thread = 1 query row ----------------
__global__ __launch_bounds__(256) void k_attn(const float* __restrict__ q, const float* __restrict__ k,
                                              const float* __restrict__ v, const float* __restrict__ smask,
                                              float* __restrict__ ao){
    __shared__ float4 kt[64][17];
    __shared__ float4 vt[64][17];
    __shared__ float  smt[64];
    int t   = threadIdx.x;
    int bh  = blockIdx.x >> 2, rt = blockIdx.x & 3;
    int b   = bh >> 4, h = bh & 15;
    int row = rt*256 + t;
    const float* qrow = q + (size_t)(bh*NL + row)*NDH;
    float4 qv[16];
    #pragma unroll
    for (int i=0;i<16;i++){
        qv[i] = ((const float4*)qrow)[i];
        qv[i].x*=0.125f; qv[i].y*=0.125f; qv[i].z*=0.125f; qv[i].w*=0.125f;
    }
    float4 ov[16];
    #pragma unroll
    for (int i=0;i<16;i++) ov[i] = make_float4(0.f,0.f,0.f,0.f);
    float mrun = NEG_MAX, lrun = 0.f;

    for (int j0=0; j0<NL; j0+=64){
        __syncthreads();
        #pragma unroll
        for (int e=0;e<4;e++){
            int idx = t + e*256;
            int r = idx>>4, c2 = idx&15;
            kt[r][c2] = ((const float4*)(k + (size_t)(bh*NL + j0 + r)*NDH))[c2];
            vt[r][c2] = ((const float4*)(v + (size_t)(bh*NL + j0 + r)*NDH))[c2];
        }
        if (t < 64) smt[t] = smask[b*NL + j0 + t];
        __syncthreads();
        for (int j=0;j<64;j++){
            float s0=0.f,s1=0.f,s2=0.f,s3=0.f;
            #pragma unroll
            for (int i=0;i<16;i+=4){
                float4 k0v=kt[j][i], k1v=kt[j][i+1], k2v=kt[j][i+2], k3v=kt[j][i+3];
                s0 += qv[i  ].x*k0v.x + qv[i  ].y*k0v.y + qv[i  ].z*k0v.z + qv[i  ].w*k0v.w;
                s1 += qv[i+1].x*k1v.x + qv[i+1].y*k1v.y + qv[i+1].z*k1v.z + qv[i+1].w*k1v.w;
                s2 += qv[i+2].x*k2v.x + qv[i+2].y*k2v.y + qv[i+2].z*k2v.z + qv[i+2].w*k2v.w;
                s3 += qv[i+3].x*k3v.x + qv[i+3].y*k3v.y + qv[i+3].z*k3v.z + qv[i+3].w*k3v.w;
            }
            float s = (s0+s1)+(s2+s3);
            s = (smt[j] > 0.f) ? s : NEG_MAX;
            if (s > mrun){
                float cc = __expf(mrun - s);   // first hit: exp(-huge)=0
                lrun *= cc;
                #pragma unroll
                for (int i=0;i<16;i++){ ov[i].x*=cc; ov[i].y*=cc; ov[i].z*=cc; ov[i].w*=cc; }
                mrun = s;
            }
            float p = __expf(s - mrun);
            lrun += p;
            #pragma unroll
            for (int i=0;i<16;i++){
                float4 vv = vt[j][i];
                ov[i].x += p*vv.x; ov[i].y += p*vv.y; ov[i].z += p*vv.z; ov[i].w += p*vv.w;
            }
        }
    }
    float inv = 1.f / lrun;                    // lrun >= 1 always (p=1 when s==mrun)
    float rm  = smask[b*NL + row];
    float sc  = inv * rm;
    float* dst = ao + (size_t)(b*NL + row)*NDIM + h*NDH;
    #pragma unroll
    for (int i=0;i<16;i++){
        float4 o = make_float4(ov[i].x*sc, ov[i].y*sc, ov[i].z*sc, ov[i].w*sc);
        ((float4*)dst)[i] = o;
    }
}

extern "C" void kernel_launch(void* const* d_in, const int* in_sizes, int n_in,
                              void* d_out, int out_size, void* d_ws, size_t ws_size,
                              hipStream_t stream) {
    const float* x      = (const float*)d_in[0];
    const float* time_  = (const float*)d_in[1];
    const float* smask  = (const float*)d_in[2];
    const float* cycm   = (const float*)d_in[3];
    const float* gamma  = (const float*)d_in[4];
    const float* Wt     = (const float*)d_in[5];
    const float* bt     = (const float*)d_in[6];
    const float* Wq     = (const float*)d_in[7];
    const float* Wkv    = (const float*)d_in[8];
    const float* Wo     = (const float*)d_in[9];
    const float* rf     = (const float*)d_in[10];
    const int*   resi   = (const int*)d_in[11];
    const int*   chain  = (const int*)d_in[12];
    float* out = (float*)d_out;

    float* ws = (float*)d_ws;
    float* silu_t = ws;                 // 4096
    float* ss     = ws + 4096;          // 8192
    float* cnts   = ws + 12288;         // 8
    float* cosb   = ws + 12296;         // 131072
    float* sinb   = ws + 143368;        // 131072
    float* xc     = ws + 274440;        // 4194304
    float* qb     = ws + 4468744;       // 4194304
    float* kb     = ws + 8663048;       // 4194304
    float* vb     = ws + 12857352;      // 4194304
    float* ao     = xc;                 // reuse (xc dead after QKV GEMMs)

    hipLaunchKernelGGL(k_silu,   dim3(16),          dim3(256), 0, stream, time_, silu_t);
    hipLaunchKernelGGL(k_ss,     dim3(2048),        dim3(256), 0, stream, silu_t, Wt, bt, ss);
    hipLaunchKernelGGL(k_counts, dim3(8),           dim3(256), 0, stream, chain, cycm, cnts);
    hipLaunchKernelGGL(k_angles, dim3(512),         dim3(256), 0, stream, resi, chain, cycm, rf, cnts, cosb, sinb);
    hipLaunchKernelGGL(k_lnmod,  dim3(4096),        dim3(256), 0, stream, x, smask, gamma, ss, xc);
    hipLaunchKernelGGL((k_gemm<1>), dim3(16,64),    dim3(256), 0, stream, xc, Wq,  qb, (float*)nullptr, smask);
    hipLaunchKernelGGL((k_gemm<2>), dim3(32,64),    dim3(256), 0, stream, xc, Wkv, kb, vb, smask);
    hipLaunchKernelGGL(k_rope,   dim3(8192),        dim3(256), 0, stream, qb, kb, cosb, sinb);
    hipLaunchKernelGGL(k_attn,   dim3(256),         dim3(256), 0, stream, qb, kb, vb, smask, ao);
    hipLaunchKernelGGL((k_gemm<3>), dim3(16,64),    dim3(256), 0, stream, ao, Wo, out, (float*)nullptr, smask);
}

// Round 2
// 250.188 us; speedup vs baseline: 5.9185x; 5.9185x over previous
//
#include <hip/hip_runtime.h>
#include <math.h>

#define NB 4
#define NL 1024
#define NDIM 1024
#define NH 16
#define NDH 64
#define NEG_MAX (-3.402823466e38f)

typedef __attribute__((ext_vector_type(4))) float fx4;
typedef __attribute__((ext_vector_type(8))) short bh8;

__device__ __forceinline__ ushort f2bf(float f){
    unsigned u = __float_as_uint(f);
    u += 0x7fff + ((u>>16)&1);
    return (ushort)(u>>16);
}
__device__ __forceinline__ float bf2f(ushort h){
    return __uint_as_float(((unsigned)h)<<16);
}
__device__ __forceinline__ void gload16(const void* g, void* l){
    __builtin_amdgcn_global_load_lds((const __attribute__((address_space(1))) void*)g,
                                     (__attribute__((address_space(3))) void*)l, 16, 0, 0);
}

// ---------------- silu(time) ----------------
__global__ __launch_bounds__(256) void k_silu(const float* __restrict__ t, float* __restrict__ o){
    int i = blockIdx.x*256 + threadIdx.x;            // NB*NDIM = 4096
    float v = t[i];
    o[i] = v / (1.f + __expf(-v));
}

// ---------------- ss = silu(time) @ Wt.T + bt ----------------
__global__ __launch_bounds__(256) void k_ss(const float* __restrict__ st, const float* __restrict__ Wt,
                                            const float* __restrict__ bt, float* __restrict__ ss){
    int gw   = (blockIdx.x*256 + threadIdx.x) >> 6;  // 0..8191
    int lane = threadIdx.x & 63;
    int b = gw >> 11, j = gw & 2047;
    const float* a = st + b*NDIM;
    const float* w = Wt + (size_t)j*NDIM;
    float s = 0.f;
    #pragma unroll 4
    for (int i = lane; i < NDIM; i += 64) s += a[i]*w[i];
    #pragma unroll
    for (int off=32; off; off>>=1) s += __shfl_xor(s, off, 64);
    if (!lane) ss[gw] = s + bt[j];
}

// ---------------- counts[b][c] ----------------
__global__ __launch_bounds__(256) void k_counts(const int* __restrict__ chain, const float* __restrict__ cyc,
                                                float* __restrict__ counts){
    int b = blockIdx.x >> 1, c = blockIdx.x & 1;
    float s = 0.f;
    for (int l = threadIdx.x; l < NL; l += 256)
        s += (chain[b*NL+l]==c) ? cyc[b*NL+l] : 0.f;
    __shared__ float red[4];
    #pragma unroll
    for (int off=32; off; off>>=1) s += __shfl_xor(s, off, 64);
    if (!(threadIdx.x & 63)) red[threadIdx.x>>6] = s;
    __syncthreads();
    if (!threadIdx.x) counts[blockIdx.x] = red[0]+red[1]+red[2]+red[3];
}

// ---------------- cos/sin angle tables [B,L,32] ----------------
__global__ __launch_bounds__(256) void k_angles(const int* __restrict__ resi, const int* __restrict__ chain,
                                                const float* __restrict__ cyc, const float* __restrict__ rf,
                                                const float* __restrict__ counts,
                                                float* __restrict__ cosb, float* __restrict__ sinb){
    int idx = blockIdx.x*256 + threadIdx.x;          // NB*NL*32
    int f  = idx & 31;
    int bl = idx >> 5;
    int b  = bl >> 10;
    float t  = (float)resi[bl];
    int   ci = chain[bl];
    float cm = cyc[bl];
    float ang;
    if (cm > 0.f) {
        float ring      = counts[b*2+ci] * cm;
        float ring_safe = fmaxf(ring, 1.f);
        float max_k     = fmaxf(floorf(ring_safe*0.5f), 1.f);
        float k_eff     = (max_k == 1.f) ? 1.f : (1.f + fmodf((float)f, max_k));
        float omega     = 6.28318530717958647692f * k_eff / ring_safe;
        ang = omega * t;
    } else {
        ang = t * rf[f] + (float)ci * rf[0];
    }
    cosb[idx] = cosf(ang);
    sinb[idx] = sinf(ang);
}

// ---------------- f32 -> bf16 convert ----------------
__global__ __launch_bounds__(256) void k_conv(const float* __restrict__ s, ushort* __restrict__ d){
    int i = (blockIdx.x*256 + threadIdx.x)*4;
    fx4 v = *(const fx4*)(s+i);
    ushort4 o; o.x=f2bf(v.x); o.y=f2bf(v.y); o.z=f2bf(v.z); o.w=f2bf(v.w);
    *(ushort4*)(d+i) = o;
}

// ---------------- layernorm + adaLN modulate -> xc (bf16) ----------------
__global__ __launch_bounds__(256) void k_lnmod(const float* __restrict__ x, const float* __restrict__ sm,
                                               const float* __restrict__ gamma, const float* __restrict__ ss,
                                               ushort* __restrict__ xc){
    int row = blockIdx.x;                            // 0..4095
    int b   = row >> 10;
    int t   = threadIdx.x;
    float msk = sm[row];
    fx4 v = ((const fx4*)(x + (size_t)row*NDIM))[t];
    v.x*=msk; v.y*=msk; v.z*=msk; v.w*=msk;
    float s1 = v.x+v.y+v.z+v.w;
    float s2 = v.x*v.x + v.y*v.y + v.z*v.z + v.w*v.w;
    __shared__ float r1[4], r2[4];
    #pragma unroll
    for (int off=32; off; off>>=1){ s1 += __shfl_xor(s1,off,64); s2 += __shfl_xor(s2,off,64); }
    if (!(t & 63)){ r1[t>>6]=s1; r2[t>>6]=s2; }
    __syncthreads();
    s1 = r1[0]+r1[1]+r1[2]+r1[3];
    s2 = r2[0]+r2[1]+r2[2]+r2[3];
    float mu  = s1 * (1.f/NDIM);
    float var = s2 * (1.f/NDIM) - mu*mu;
    float rs  = rsqrtf(var + 1e-5f);
    const float* sc = ss + b*2048;
    fx4 g   = ((const fx4*)gamma)[t];
    fx4 scl = ((const fx4*)sc)[t];
    fx4 sh  = ((const fx4*)(sc+1024))[t];
    ushort4 ob;
    ob.x = f2bf((v.x-mu)*rs*g.x*(1.f+scl.x)+sh.x);
    ob.y = f2bf((v.y-mu)*rs*g.y*(1.f+scl.y)+sh.y);
    ob.z = f2bf((v.z-mu)*rs*g.z*(1.f+scl.z)+sh.z);
    ob.w = f2bf((v.w-mu)*rs*g.w*(1.f+scl.w)+sh.w);
    *(ushort4*)(xc + (size_t)row*NDIM + t*4) = ob;
}

// ---------------- bf16 MFMA GEMM (m97 structure): C = A @ W^T ----------------
// A [M][1024] bf16, W [N][1024] bf16. MODE 0: N=3072, split q/k/v -> [B,H,L,DH] bf16.
// MODE 1: N=1024, f32 out * seq_mask.
template<int MODE>
__global__ __launch_bounds__(256) void k_mm(const ushort* __restrict__ A, const ushort* __restrict__ W,
                                            ushort* __restrict__ qo, ushort* __restrict__ ko,
                                            ushort* __restrict__ vo,
                                            float* __restrict__ outf, const float* __restrict__ smask){
    __shared__ ushort As[128*32];
    __shared__ ushort Bs[128*32];
    int t = threadIdx.x, l = t&63, w = t>>6;
    int lo = l&15, hi = l>>4;
    int m0 = blockIdx.y*128, n0 = blockIdx.x*128;
    int wm = (w>>1)*64, wn = (w&1)*64;
    fx4 acc[4][4];
    #pragma unroll
    for (int i=0;i<4;i++)
        #pragma unroll
        for (int j=0;j<4;j++) acc[i][j] = (fx4){0.f,0.f,0.f,0.f};
    const char* Ab = (const char*)A;
    const char* Wb = (const char*)W;
    for (int k0=0; k0<NDIM; k0+=32){
        __syncthreads();
        #pragma unroll
        for (int e=0;e<2;e++){
            int c = t + e*256;
            int row = c>>2, cw = c&3;
            gload16(Ab + (size_t)(m0+row)*2048 + k0*2 + cw*16, (char*)As + c*16);
            gload16(Wb + (size_t)(n0+row)*2048 + k0*2 + cw*16, (char*)Bs + c*16);
        }
        __syncthreads();
        bh8 af[4], bf[4];
        #pragma unroll
        for (int i=0;i<4;i++) af[i] = *(const bh8*)(As + (wm + i*16 + lo)*32 + hi*8);
        #pragma unroll
        for (int j=0;j<4;j++) bf[j] = *(const bh8*)(Bs + (wn + j*16 + lo)*32 + hi*8);
        #pragma unroll
        for (int i=0;i<4;i++)
            #pragma unroll
            for (int j=0;j<4;j++)
                acc[i][j] = __builtin_amdgcn_mfma_f32_16x16x32_bf16(af[i], bf[j], acc[i][j], 0, 0, 0);
    }
    #pragma unroll
    for (int i=0;i<4;i++){
        #pragma unroll
        for (int r=0;r<4;r++){
            int m = m0 + wm + i*16 + hi*4 + r;
            int b_ = m>>10, l_ = m&1023;
            #pragma unroll
            for (int j=0;j<4;j++){
                int n = n0 + wn + j*16 + lo;
                float val = acc[i][j][r];
                if (MODE==0){
                    int nn = n & 1023;
                    int h_ = nn>>6, d_ = nn&63;
                    size_t off = (size_t)((b_*NH + h_)*NL + l_)*NDH + d_;
                    if (n < 1024)      qo[off] = f2bf(val);
                    else if (n < 2048) ko[off] = f2bf(val);
                    else               vo[off] = f2bf(val);
                } else {
                    outf[(size_t)m*NDIM + n] = val * smask[m];
                }
            }
        }
    }
}

// ---------------- RoPE on bf16 q,k (q also * DH^-0.5) ----------------
__global__ __launch_bounds__(256) void k_rope(ushort* __restrict__ q, ushort* __restrict__ k,
                                              const float* __restrict__ cosb, const float* __restrict__ sinb){
    int idx = blockIdx.x*256 + threadIdx.x;          // NB*NH*NL*32
    int f   = idx & 31;
    int bhl = idx >> 5;
    int l   = bhl & 1023;
    int b   = bhl >> 14;
    int ca  = ((b<<10)|l)*32 + f;
    float c = cosb[ca], s = sinb[ca];
    unsigned qp = ((const unsigned*)q)[idx];
    unsigned kp = ((const unsigned*)k)[idx];
    float qx = bf2f((ushort)(qp&0xffffu)), qy = bf2f((ushort)(qp>>16));
    float kx = bf2f((ushort)(kp&0xffffu)), ky = bf2f((ushort)(kp>>16));
    float q0 = (qx*c - qy*s)*0.125f, q1 = (qy*c + qx*s)*0.125f;
    float k0 = kx*c - ky*s,          k1 = ky*c + kx*s;
    ((unsigned*)q)[idx] = (unsigned)f2bf(q0) | ((unsigned)f2bf(q1)<<16);
    ((unsigned*)k)[idx] = (unsigned)f2bf(k0) | ((unsigned)f2bf(k1)<<16);
}

// ---------------- v [bh][l][dh] -> vt [bh][dh][l] (bf16) ----------------
__global__ __launch_bounds__(256) void k_vt(const ushort* __restrict__ v, ushort* __restrict__ vt){
    __shared__ ushort tile[64][65];
    int t = threadIdx.x;
    int bh = blockIdx.y, l0 = blockIdx.x*64;
    #pragma unroll
    for (int e=0;e<2;e++){
        int c = t + e*256;
        int row = c>>3, cw = c&7;
        bh8 d = *(const bh8*)(v + ((size_t)bh*NL + l0 + row)*NDH + cw*8);
        #pragma unroll
        for (int x=0;x<8;x++) tile[row][cw*8+x] = (ushort)d[x];
    }
    __syncthreads();
    #pragma unroll
    for (int e=0;e<2;e++){
        int c = t + e*256;
        int drow = c>>3, cw = c&7;
        bh8 o;
        #pragma unroll
        for (int x=0;x<8;x++) o[x] = (short)tile[cw*8+x][drow];
        *(bh8*)(vt + ((size_t)bh*NDH + drow)*NL + l0 + cw*8) = o;
    }
}

// ---------------- MFMA flash attention ----------------
// grid (16 qtiles, 64 bh), 256 thr = 4 waves; wave owns 16 q-rows.
__global__ __launch_bounds__(256) void k_fattn(const ushort* __restrict__ qb, const ushort* __restrict__ kb,
                                               const ushort* __restrict__ vt, const float* __restrict__ smask,
                                               ushort* __restrict__ ao){
    __shared__ ushort Ks[64*64];        // K tile  [kv][dh]   (xor-swizzled rows)
    __shared__ ushort Vs[64*64];        // Vt tile [dh][kv]   (xor-swizzled rows)
    __shared__ ushort Ps[4][16*64];     // per-wave P [q][kv] (xor-swizzled rows)
    __shared__ float  smt[64];
    int t = threadIdx.x, l = t&63, w = t>>6;
    int bh = blockIdx.y, b = bh>>4, h = bh&15;
    int q0 = blockIdx.x*64;
    int lo = l&15, hi = l>>4;

    const ushort* qrowp = qb + ((size_t)bh*NL + q0 + w*16 + lo)*NDH;
    bh8 aq0 = *(const bh8*)(qrowp + hi*8);
    bh8 aq1 = *(const bh8*)(qrowp + 32 + hi*8);

    fx4 o[4];
    float mrun[4], lrun[4];
    #pragma unroll
    for (int d=0;d<4;d++) o[d] = (fx4){0.f,0.f,0.f,0.f};
    #pragma unroll
    for (int r=0;r<4;r++){ mrun[r]=NEG_MAX; lrun[r]=0.f; }

    const char* kbase = (const char*)(kb + (size_t)bh*NL*NDH);
    const char* vbase = (const char*)(vt + (size_t)bh*NDH*NL);
    char* KsB = (char*)Ks;
    char* VsB = (char*)Vs;
    char* PsB = (char*)&Ps[w][0];

    for (int j0=0; j0<NL; j0+=64){
        __syncthreads();
        #pragma unroll
        for (int e=0;e<2;e++){
            int c = t + e*256;
            int row = c>>3, cw = c&7;
            int lc = cw ^ (row&7);          // pre-swizzled source chunk (T21)
            gload16(kbase + (size_t)(j0+row)*128 + lc*16, KsB + c*16);
            gload16(vbase + (size_t)row*2048 + j0*2 + lc*16, VsB + c*16);
        }
        if (t < 64) smt[t] = smask[b*NL + j0 + t];
        __syncthreads();

        // ---- S = Q K^T (per wave: 16 q x 64 kv) ----
        fx4 s[4];
        #pragma unroll
        for (int j=0;j<4;j++){
            int row = j*16 + lo;
            int swz = (row&7)<<4;
            bh8 bk0 = *(const bh8*)(KsB + row*128 + ((hi*16) ^ swz));
            bh8 bk1 = *(const bh8*)(KsB + row*128 + ((64 + hi*16) ^ swz));
            fx4 z = (fx4){0.f,0.f,0.f,0.f};
            z = __builtin_amdgcn_mfma_f32_16x16x32_bf16(aq0, bk0, z, 0,0,0);
            z = __builtin_amdgcn_mfma_f32_16x16x32_bf16(aq1, bk1, z, 0,0,0);
            float msk = smt[row];
            s[j] = (msk > 0.f) ? z : (fx4){NEG_MAX,NEG_MAX,NEG_MAX,NEG_MAX};
        }

        // ---- online softmax (rows distributed: row = hi*4+r over 16-lane groups) ----
        float p[4][4];
        #pragma unroll
        for (int r=0;r<4;r++){
            float mt = fmaxf(fmaxf(s[0][r],s[1][r]), fmaxf(s[2][r],s[3][r]));
            #pragma unroll
            for (int off=1; off<16; off<<=1) mt = fmaxf(mt, __shfl_xor(mt, off));
            float mnew = fmaxf(mrun[r], mt);
            float cc = __expf(mrun[r]-mnew);
            float rs = 0.f;
            #pragma unroll
            for (int j=0;j<4;j++){ p[j][r] = __expf(s[j][r]-mnew); rs += p[j][r]; }
            #pragma unroll
            for (int off=1; off<16; off<<=1) rs += __shfl_xor(rs, off);
            lrun[r] = lrun[r]*cc + rs;
            mrun[r] = mnew;
            #pragma unroll
            for (int d=0;d<4;d++) o[d][r] *= cc;
        }

        // ---- P -> wave-private LDS (C-layout scatter, swizzled) ----
        #pragma unroll
        for (int r=0;r<4;r++){
            int qr = hi*4 + r;
            int swz = (qr&7)<<4;
            #pragma unroll
            for (int j=0;j<4;j++){
                int kv = j*16 + lo;
                *(ushort*)(PsB + qr*128 + ((kv*2) ^ swz)) = f2bf(p[j][r]);
            }
        }
        // ---- P as A-frags (wave-local, compiler inserts lgkm waits) ----
        int swq = (lo&7)<<4;
        bh8 ap0 = *(const bh8*)(PsB + lo*128 + ((hi*16) ^ swq));
        bh8 ap1 = *(const bh8*)(PsB + lo*128 + ((64 + hi*16) ^ swq));

        // ---- O += P V  (B-frag from Vt tile) ----
        #pragma unroll
        for (int d=0;d<4;d++){
            int row = d*16 + lo;
            int swz = (row&7)<<4;
            bh8 bv0 = *(const bh8*)(VsB + row*128 + ((hi*16) ^ swz));
            bh8 bv1 = *(const bh8*)(VsB + row*128 + ((64 + hi*16) ^ swz));
            o[d] = __builtin_amdgcn_mfma_f32_16x16x32_bf16(ap0, bv0, o[d], 0,0,0);
            o[d] = __builtin_amdgcn_mfma_f32_16x16x32_bf16(ap1, bv1, o[d], 0,0,0);
        }
    }

    #pragma unroll
    for (int r=0;r<4;r++){
        float inv = 1.f / lrun[r];
        int l_ = q0 + w*16 + hi*4 + r;
        size_t base = ((size_t)b*NL + l_)*NDIM + h*NDH;
        #pragma unroll
        for (int d=0;d<4;d++)
            ao[base + d*16 + lo] = f2bf(o[d][r]*inv);
    }
}

extern "C" void kernel_launch(void* const* d_in, const int* in_sizes, int n_in,
                              void* d_out, int out_size, void* d_ws, size_t ws_size,
                              hipStream_t stream) {
    const float* x      = (const float*)d_in[0];
    const float* time_  = (const float*)d_in[1];
    const float* smask  = (const float*)d_in[2];
    const float* cycm   = (const float*)d_in[3];
    const float* gamma  = (const float*)d_in[4];
    const float* Wt     = (const float*)d_in[5];
    const float* bt     = (const float*)d_in[6];
    const float* Wq     = (const float*)d_in[7];
    const float* Wkv    = (const float*)d_in[8];
    const float* Wo     = (const float*)d_in[9];
    const float* rf     = (const float*)d_in[10];
    const int*   resi   = (const int*)d_in[11];
    const int*   chain  = (const int*)d_in[12];
    float* out = (float*)d_out;

    float*  silu_t = (float*)d_ws;                   // 4096
    float*  ss     = silu_t + 4096;                  // 8192
    float*  cnts   = ss + 8192;                      // 16 (pad)
    float*  cosb   = cnts + 16;                      // 131072
    float*  sinb   = cosb + 131072;                  // 131072
    ushort* xc     = (ushort*)(sinb + 131072);       // 4096*1024
    ushort* wqkv   = xc + 4194304;                   // 3072*1024
    ushort* wo     = wqkv + 3145728;                 // 1024*1024
    ushort* qbuf   = wo + 1048576;                   // 4*16*1024*64
    ushort* kbuf   = qbuf + 4194304;
    ushort* vbuf   = kbuf + 4194304;
    ushort* vtb    = vbuf + 4194304;
    ushort* aob    = vtb + 4194304;

    hipLaunchKernelGGL(k_silu,   dim3(16),        dim3(256), 0, stream, time_, silu_t);
    hipLaunchKernelGGL(k_ss,     dim3(2048),      dim3(256), 0, stream, silu_t, Wt, bt, ss);
    hipLaunchKernelGGL(k_counts, dim3(8),         dim3(256), 0, stream, chain, cycm, cnts);
    hipLaunchKernelGGL(k_angles, dim3(512),       dim3(256), 0, stream, resi, chain, cycm, rf, cnts, cosb, sinb);
    hipLaunchKernelGGL(k_conv,   dim3(1024),      dim3(256), 0, stream, Wq,  wqkv);
    hipLaunchKernelGGL(k_conv,   dim3(2048),      dim3(256), 0, stream, Wkv, wqkv + 1048576);
    hipLaunchKernelGGL(k_conv,   dim3(1024),      dim3(256), 0, stream, Wo,  wo);
    hipLaunchKernelGGL(k_lnmod,  dim3(4096),      dim3(256), 0, stream, x, smask, gamma, ss, xc);
    hipLaunchKernelGGL((k_mm<0>), dim3(24,32),    dim3(256), 0, stream, xc, wqkv, qbuf, kbuf, vbuf, (float*)nullptr, (const float*)nullptr);
    hipLaunchKernelGGL(k_rope,   dim3(8192),      dim3(256), 0, stream, qbuf, kbuf, cosb, sinb);
    hipLaunchKernelGGL(k_vt,     dim3(16,64),     dim3(256), 0, stream, vbuf, vtb);
    hipLaunchKernelGGL(k_fattn,  dim3(16,64),     dim3(256), 0, stream, qbuf, kbuf, vtb, smask, aob);
    hipLaunchKernelGGL((k_mm<1>), dim3(8,32),     dim3(256), 0, stream, aob, wo, (ushort*)nullptr, (ushort*)nullptr, (ushort*)nullptr, out, smask);
}

// Round 4
// 230.690 us; speedup vs baseline: 6.4187x; 1.0845x over previous
//
#include <hip/hip_runtime.h>
#include <hip/hip_bf16.h>
#include <math.h>

#define NB 4
#define NL 1024
#define NDIM 1024
#define NH 16
#define NDH 64
#define NEG_MAX (-3.402823466e38f)

typedef __attribute__((ext_vector_type(4))) float fx4;
typedef __attribute__((ext_vector_type(8))) short bh8;

__device__ __forceinline__ ushort f2bf(float f){
    __hip_bfloat16 h = __float2bfloat16(f);   // RNE, compiler fuses pairs to cvt_pk
    return *(ushort*)&h;
}
__device__ __forceinline__ float bf2f(ushort h){
    return __uint_as_float(((unsigned)h)<<16);
}
__device__ __forceinline__ void gload16(const void* g, void* l){
    __builtin_amdgcn_global_load_lds((const __attribute__((address_space(1))) void*)g,
                                     (__attribute__((address_space(3))) void*)l, 16, 0, 0);
}

// ---------------- ss = silu(time) @ Wt.T + bt  (silu fused) ----------------
__global__ __launch_bounds__(256) void k_ss(const float* __restrict__ time_, const float* __restrict__ Wt,
                                            const float* __restrict__ bt, float* __restrict__ ss){
    int gw   = (blockIdx.x*256 + threadIdx.x) >> 6;  // 0..8191
    int lane = threadIdx.x & 63;
    int b = gw >> 11, j = gw & 2047;
    const float* a = time_ + b*NDIM;
    const float* w = Wt + (size_t)j*NDIM;
    float s = 0.f;
    #pragma unroll 4
    for (int i = lane; i < NDIM; i += 64){
        float v = a[i];
        s += (v / (1.f + __expf(-v))) * w[i];
    }
    #pragma unroll
    for (int off=32; off; off>>=1) s += __shfl_xor(s, off, 64);
    if (!lane) ss[gw] = s + bt[j];
}

// ---------------- counts[b][c] ----------------
__global__ __launch_bounds__(256) void k_counts(const int* __restrict__ chain, const float* __restrict__ cyc,
                                                float* __restrict__ counts){
    int b = blockIdx.x >> 1, c = blockIdx.x & 1;
    float s = 0.f;
    for (int l = threadIdx.x; l < NL; l += 256)
        s += (chain[b*NL+l]==c) ? cyc[b*NL+l] : 0.f;
    __shared__ float red[4];
    #pragma unroll
    for (int off=32; off; off>>=1) s += __shfl_xor(s, off, 64);
    if (!(threadIdx.x & 63)) red[threadIdx.x>>6] = s;
    __syncthreads();
    if (!threadIdx.x) counts[blockIdx.x] = red[0]+red[1]+red[2]+red[3];
}

// ---------------- cos/sin angle tables [B,L,32] ----------------
__global__ __launch_bounds__(256) void k_angles(const int* __restrict__ resi, const int* __restrict__ chain,
                                                const float* __restrict__ cyc, const float* __restrict__ rf,
                                                const float* __restrict__ counts,
                                                float* __restrict__ cosb, float* __restrict__ sinb){
    int idx = blockIdx.x*256 + threadIdx.x;          // NB*NL*32
    int f  = idx & 31;
    int bl = idx >> 5;
    int b  = bl >> 10;
    float t  = (float)resi[bl];
    int   ci = chain[bl];
    float cm = cyc[bl];
    float ang;
    if (cm > 0.f) {
        float ring      = counts[b*2+ci] * cm;
        float ring_safe = fmaxf(ring, 1.f);
        float max_k     = fmaxf(floorf(ring_safe*0.5f), 1.f);
        float k_eff     = (max_k == 1.f) ? 1.f : (1.f + fmodf((float)f, max_k));
        float omega     = 6.28318530717958647692f * k_eff / ring_safe;
        ang = omega * t;
    } else {
        ang = t * rf[f] + (float)ci * rf[0];
    }
    cosb[idx] = cosf(ang);
    sinb[idx] = sinf(ang);
}

// ---------------- fused f32->bf16 convert: Wq|Wkv -> wqkv, Wo -> wo ----------------
// total = 1048576 + 2097152 + 1048576 = 4194304 elems -> grid 4096 x 256 x vec4
__global__ __launch_bounds__(256) void k_convall(const float* __restrict__ Wq, const float* __restrict__ Wkv,
                                                 const float* __restrict__ Wo,
                                                 ushort* __restrict__ wqkv, ushort* __restrict__ wo){
    int i = (blockIdx.x*256 + threadIdx.x)*4;
    if (i >= 4194304) return;
    const float* src; ushort* dst;
    if (i < 3145728){
        dst = wqkv + i;
        src = (i < 1048576) ? (Wq + i) : (Wkv + (i - 1048576));
    } else {
        dst = wo + (i - 3145728);
        src = Wo + (i - 3145728);
    }
    fx4 v = *(const fx4*)src;
    ushort4 o; o.x=f2bf(v.x); o.y=f2bf(v.y); o.z=f2bf(v.z); o.w=f2bf(v.w);
    *(ushort4*)dst = o;
}

// ---------------- layernorm + adaLN modulate -> xc (bf16) ----------------
__global__ __launch_bounds__(256) void k_lnmod(const float* __restrict__ x, const float* __restrict__ sm,
                                               const float* __restrict__ gamma, const float* __restrict__ ss,
                                               ushort* __restrict__ xc){
    int row = blockIdx.x;                            // 0..4095
    int b   = row >> 10;
    int t   = threadIdx.x;
    float msk = sm[row];
    fx4 v = ((const fx4*)(x + (size_t)row*NDIM))[t];
    v.x*=msk; v.y*=msk; v.z*=msk; v.w*=msk;
    float s1 = v.x+v.y+v.z+v.w;
    float s2 = v.x*v.x + v.y*v.y + v.z*v.z + v.w*v.w;
    __shared__ float r1[4], r2[4];
    #pragma unroll
    for (int off=32; off; off>>=1){ s1 += __shfl_xor(s1,off,64); s2 += __shfl_xor(s2,off,64); }
    if (!(t & 63)){ r1[t>>6]=s1; r2[t>>6]=s2; }
    __syncthreads();
    s1 = r1[0]+r1[1]+r1[2]+r1[3];
    s2 = r2[0]+r2[1]+r2[2]+r2[3];
    float mu  = s1 * (1.f/NDIM);
    float var = s2 * (1.f/NDIM) - mu*mu;
    float rs  = rsqrtf(var + 1e-5f);
    const float* sc = ss + b*2048;
    fx4 g   = ((const fx4*)gamma)[t];
    fx4 scl = ((const fx4*)sc)[t];
    fx4 sh  = ((const fx4*)(sc+1024))[t];
    ushort4 ob;
    ob.x = f2bf((v.x-mu)*rs*g.x*(1.f+scl.x)+sh.x);
    ob.y = f2bf((v.y-mu)*rs*g.y*(1.f+scl.y)+sh.y);
    ob.z = f2bf((v.z-mu)*rs*g.z*(1.f+scl.z)+sh.z);
    ob.w = f2bf((v.w-mu)*rs*g.w*(1.f+scl.w)+sh.w);
    *(ushort4*)(xc + (size_t)row*NDIM + t*4) = ob;
}

// ---------------- bf16 MFMA GEMM (m97 structure): C = A @ W^T ----------------
template<int MODE>
__global__ __launch_bounds__(256) void k_mm(const ushort* __restrict__ A, const ushort* __restrict__ W,
                                            ushort* __restrict__ qo, ushort* __restrict__ ko,
                                            ushort* __restrict__ vo,
                                            float* __restrict__ outf, const float* __restrict__ smask){
    __shared__ ushort As[128*32];
    __shared__ ushort Bs[128*32];
    int t = threadIdx.x, l = t&63, w = t>>6;
    int lo = l&15, hi = l>>4;
    int m0 = blockIdx.y*128, n0 = blockIdx.x*128;
    int wm = (w>>1)*64, wn = (w&1)*64;
    fx4 acc[4][4];
    #pragma unroll
    for (int i=0;i<4;i++)
        #pragma unroll
        for (int j=0;j<4;j++) acc[i][j] = (fx4){0.f,0.f,0.f,0.f};
    const char* Ab = (const char*)A;
    const char* Wb = (const char*)W;
    for (int k0=0; k0<NDIM; k0+=32){
        __syncthreads();
        #pragma unroll
        for (int e=0;e<2;e++){
            int c = t + e*256;
            int row = c>>2, cw = c&3;
            gload16(Ab + (size_t)(m0+row)*2048 + k0*2 + cw*16, (char*)As + c*16);
            gload16(Wb + (size_t)(n0+row)*2048 + k0*2 + cw*16, (char*)Bs + c*16);
        }
        __syncthreads();
        bh8 af[4], bf[4];
        #pragma unroll
        for (int i=0;i<4;i++) af[i] = *(const bh8*)(As + (wm + i*16 + lo)*32 + hi*8);
        #pragma unroll
        for (int j=0;j<4;j++) bf[j] = *(const bh8*)(Bs + (wn + j*16 + lo)*32 + hi*8);
        #pragma unroll
        for (int i=0;i<4;i++)
            #pragma unroll
            for (int j=0;j<4;j++)
                acc[i][j] = __builtin_amdgcn_mfma_f32_16x16x32_bf16(af[i], bf[j], acc[i][j], 0, 0, 0);
    }
    #pragma unroll
    for (int i=0;i<4;i++){
        #pragma unroll
        for (int r=0;r<4;r++){
            int m = m0 + wm + i*16 + hi*4 + r;
            int b_ = m>>10, l_ = m&1023;
            #pragma unroll
            for (int j=0;j<4;j++){
                int n = n0 + wn + j*16 + lo;
                float val = acc[i][j][r];
                if (MODE==0){
                    int nn = n & 1023;
                    int h_ = nn>>6, d_ = nn&63;
                    size_t off = (size_t)((b_*NH + h_)*NL + l_)*NDH + d_;
                    if (n < 1024)      qo[off] = f2bf(val);
                    else if (n < 2048) ko[off] = f2bf(val);
                    else               vo[off] = f2bf(val);
                } else {
                    outf[(size_t)m*NDIM + n] = val * smask[m];
                }
            }
        }
    }
}

// ---------------- RoPE on bf16 q,k (q also * DH^-0.5 * log2e for exp2 softmax) ----------------
__global__ __launch_bounds__(256) void k_rope(ushort* __restrict__ q, ushort* __restrict__ k,
                                              const float* __restrict__ cosb, const float* __restrict__ sinb){
    int idx = blockIdx.x*256 + threadIdx.x;          // NB*NH*NL*32
    int f   = idx & 31;
    int bhl = idx >> 5;
    int l   = bhl & 1023;
    int b   = bhl >> 14;
    int ca  = ((b<<10)|l)*32 + f;
    float c = cosb[ca], s = sinb[ca];
    const float QS = 0.18033688011112042f;           // 0.125 * log2(e)
    unsigned qp = ((const unsigned*)q)[idx];
    unsigned kp = ((const unsigned*)k)[idx];
    float qx = bf2f((ushort)(qp&0xffffu)), qy = bf2f((ushort)(qp>>16));
    float kx = bf2f((ushort)(kp&0xffffu)), ky = bf2f((ushort)(kp>>16));
    float q0 = (qx*c - qy*s)*QS, q1 = (qy*c + qx*s)*QS;
    float k0 = kx*c - ky*s,      k1 = ky*c + kx*s;
    ((unsigned*)q)[idx] = (unsigned)f2bf(q0) | ((unsigned)f2bf(q1)<<16);
    ((unsigned*)k)[idx] = (unsigned)f2bf(k0) | ((unsigned)f2bf(k1)<<16);
}

// ---------------- v [bh][l][dh] -> vt [bh][dh][l] (bf16) ----------------
__global__ __launch_bounds__(256) void k_vt(const ushort* __restrict__ v, ushort* __restrict__ vt){
    __shared__ ushort tile[64][65];
    int t = threadIdx.x;
    int bh = blockIdx.y, l0 = blockIdx.x*64;
    #pragma unroll
    for (int e=0;e<2;e++){
        int c = t + e*256;
        int row = c>>3, cw = c&7;
        bh8 d = *(const bh8*)(v + ((size_t)bh*NL + l0 + row)*NDH + cw*8);
        #pragma unroll
        for (int x=0;x<8;x++) tile[row][cw*8+x] = (ushort)d[x];
    }
    __syncthreads();
    #pragma unroll
    for (int e=0;e<2;e++){
        int c = t + e*256;
        int drow = c>>3, cw = c&7;
        bh8 o;
        #pragma unroll
        for (int x=0;x<8;x++) o[x] = (short)tile[cw*8+x][drow];
        *(bh8*)(vt + ((size_t)bh*NDH + drow)*NL + l0 + cw*8) = o;
    }
}

// ---------------- MFMA flash attention v3 ----------------
// Swapped QK^T (lane-local softmax rows), QBLK=128 (wave=32 q), KVB=64,
// double-buffered K/V via global_load_lds, XCD-chunked grid. grid=512, 256 thr.
__global__ __launch_bounds__(256) void k_fattn(const ushort* __restrict__ qb, const ushort* __restrict__ kb,
                                               const ushort* __restrict__ vt, const float* __restrict__ smask,
                                               ushort* __restrict__ ao){
    __shared__ ushort Ks[2][64*64];     // [kv][dh], xor-swizzled rows
    __shared__ ushort Vs[2][64*64];     // [dh][kv], xor-swizzled rows
    __shared__ ushort Ps[4][32*64];     // per-wave P [q][kv], xor-swizzled rows
    int t = threadIdx.x, l = t&63, w = t>>6;
    int lo = l&15, hi = l>>4;
    // XCD-chunked swizzle: 512 blocks -> xcd gets 8 bh x 8 qtiles contiguous
    int logical = (blockIdx.x & 7)*64 + (blockIdx.x >> 3);
    int bh = logical >> 3;              // 0..63
    int qt = logical & 7;               // 0..7
    int b = bh>>4, h = bh&15;
    int q0 = qt*128;
    int swzq = (lo&7)<<4;

    // Q fragments (B-operand): rows q = q0 + w*32 + qs*16 + lo
    bh8 aq[2][2];
    #pragma unroll
    for (int qs=0; qs<2; qs++){
        const ushort* qrow = qb + ((size_t)bh*NL + q0 + w*32 + qs*16 + lo)*NDH;
        aq[qs][0] = *(const bh8*)(qrow + hi*8);
        aq[qs][1] = *(const bh8*)(qrow + 32 + hi*8);
    }
    const float* mrow = smask + b*NL;

    fx4 o[2][4];
    float mrun[2], lrun[2];
    #pragma unroll
    for (int qs=0; qs<2; qs++){
        mrun[qs]=NEG_MAX; lrun[qs]=0.f;
        #pragma unroll
        for (int dt=0; dt<4; dt++) o[qs][dt] = (fx4){0.f,0.f,0.f,0.f};
    }

    const char* kbase = (const char*)(kb + (size_t)bh*NL*NDH);
    const char* vbase = (const char*)(vt + (size_t)bh*NDH*NL);

    // stage tile jt into buffer bb (pre-swizzled global source, linear LDS dest)
    #define STAGE(bb, jt) { \
        int j0s = (jt)*64; \
        _Pragma("unroll") \
        for (int e=0;e<2;e++){ \
            int c = t + e*256; \
            int row = c>>3, cw = c&7; \
            int lc = cw ^ (row&7); \
            gload16(kbase + (size_t)(j0s+row)*128 + lc*16, (char*)Ks[bb] + c*16); \
        } \
        _Pragma("unroll") \
        for (int e=0;e<2;e++){ \
            int c = t + e*256; \
            int row = c>>3, cw = c&7; \
            int lc = cw ^ (row&7); \
            gload16(vbase + (size_t)row*2048 + j0s*2 + lc*16, (char*)Vs[bb] + c*16); \
        } }

    STAGE(0, 0);
    __syncthreads();

    for (int tt=0; tt<16; ++tt){
        int cur = tt & 1;
        if (tt < 15) STAGE(cur^1, tt+1);
        int j0 = tt*64;
        const char* KsB = (const char*)Ks[cur];
        const char* VsB = (const char*)Vs[cur];
        char* PsB = (char*)&Ps[w][0];

        // ---- S^T = K Q^T : D[kv][q], col=q=lo, row=kv=j*16+hi*4+r ----
        bh8 kf[4][2];
        #pragma unroll
        for (int j=0;j<4;j++){
            int row = j*16 + lo;
            int swz = (row&7)<<4;
            kf[j][0] = *(const bh8*)(KsB + row*128 + ((hi*16) ^ swz));
            kf[j][1] = *(const bh8*)(KsB + row*128 + ((64 + hi*16) ^ swz));
        }
        fx4 s[2][4];
        #pragma unroll
        for (int qs=0; qs<2; qs++)
            #pragma unroll
            for (int j=0;j<4;j++){
                fx4 z = (fx4){0.f,0.f,0.f,0.f};
                z = __builtin_amdgcn_mfma_f32_16x16x32_bf16(kf[j][0], aq[qs][0], z, 0,0,0);
                z = __builtin_amdgcn_mfma_f32_16x16x32_bf16(kf[j][1], aq[qs][1], z, 0,0,0);
                s[qs][j] = z;
            }
        // ---- mask (per kv; all-ones in this problem, kept for semantics) ----
        #pragma unroll
        for (int j=0;j<4;j++){
            float4 mv = *(const float4*)(mrow + j0 + j*16 + hi*4);
            s[0][j][0] = mv.x>0.f ? s[0][j][0] : NEG_MAX;  s[1][j][0] = mv.x>0.f ? s[1][j][0] : NEG_MAX;
            s[0][j][1] = mv.y>0.f ? s[0][j][1] : NEG_MAX;  s[1][j][1] = mv.y>0.f ? s[1][j][1] : NEG_MAX;
            s[0][j][2] = mv.z>0.f ? s[0][j][2] : NEG_MAX;  s[1][j][2] = mv.z>0.f ? s[1][j][2] : NEG_MAX;
            s[0][j][3] = mv.w>0.f ? s[0][j][3] : NEG_MAX;  s[1][j][3] = mv.w>0.f ? s[1][j][3] : NEG_MAX;
        }

        // ---- online softmax: lane-local rows (q = qs*16 + lo), exp2 domain ----
        #pragma unroll
        for (int qs=0; qs<2; qs++){
            float mt = s[qs][0][0];
            #pragma unroll
            for (int j=0;j<4;j++)
                #pragma unroll
                for (int r=0;r<4;r++) mt = fmaxf(mt, s[qs][j][r]);
            mt = fmaxf(mt, __shfl_xor(mt, 16));
            mt = fmaxf(mt, __shfl_xor(mt, 32));
            float mnew = fmaxf(mrun[qs], mt);
            float cc = __builtin_amdgcn_exp2f(mrun[qs] - mnew);
            float p[4][4];
            float rs = 0.f;
            #pragma unroll
            for (int j=0;j<4;j++)
                #pragma unroll
                for (int r=0;r<4;r++){ p[j][r] = __builtin_amdgcn_exp2f(s[qs][j][r] - mnew); rs += p[j][r]; }
            rs += __shfl_xor(rs, 16);
            rs += __shfl_xor(rs, 32);
            lrun[qs] = lrun[qs]*cc + rs;
            mrun[qs] = mnew;
            // broadcast cc to O-rows (q = hi*4+r) and rescale O
            #pragma unroll
            for (int r=0;r<4;r++){
                float ccr = __shfl(cc, hi*4 + r);
                #pragma unroll
                for (int dt=0; dt<4; dt++) o[qs][dt][r] *= ccr;
            }
            // pack P (bf16 pairs) -> wave-private swizzled LDS
            #pragma unroll
            for (int j=0;j<4;j++)
                #pragma unroll
                for (int pp=0; pp<2; pp++){
                    unsigned word = (unsigned)f2bf(p[j][2*pp]) | ((unsigned)f2bf(p[j][2*pp+1])<<16);
                    int kv0 = j*16 + hi*4 + 2*pp;
                    *(unsigned*)(PsB + (qs*16+lo)*128 + ((kv0*2) ^ swzq)) = word;
                }
        }

        // ---- P A-frags + O += P V ----
        bh8 ap[2][2];
        #pragma unroll
        for (int qs=0; qs<2; qs++){
            ap[qs][0] = *(const bh8*)(PsB + (qs*16+lo)*128 + ((hi*16) ^ swzq));
            ap[qs][1] = *(const bh8*)(PsB + (qs*16+lo)*128 + ((64 + hi*16) ^ swzq));
        }
        #pragma unroll
        for (int dt=0; dt<4; dt++){
            int row = dt*16 + lo;
            int swz = (row&7)<<4;
            bh8 bv0 = *(const bh8*)(VsB + row*128 + ((hi*16) ^ swz));
            bh8 bv1 = *(const bh8*)(VsB + row*128 + ((64 + hi*16) ^ swz));
            o[0][dt] = __builtin_amdgcn_mfma_f32_16x16x32_bf16(ap[0][0], bv0, o[0][dt], 0,0,0);
            o[0][dt] = __builtin_amdgcn_mfma_f32_16x16x32_bf16(ap[0][1], bv1, o[0][dt], 0,0,0);
            o[1][dt] = __builtin_amdgcn_mfma_f32_16x16x32_bf16(ap[1][0], bv0, o[1][dt], 0,0,0);
            o[1][dt] = __builtin_amdgcn_mfma_f32_16x16x32_bf16(ap[1][1], bv1, o[1][dt], 0,0,0);
        }
        __syncthreads();
    }
    #undef STAGE

    // ---- epilogue: normalize, store [B,L,H*DH] bf16 ----
    #pragma unroll
    for (int qs=0; qs<2; qs++){
        float inv = 1.f / lrun[qs];
        #pragma unroll
        for (int r=0;r<4;r++){
            float ivr = __shfl(inv, hi*4 + r);
            int l_ = q0 + w*32 + qs*16 + hi*4 + r;
            size_t base = ((size_t)b*NL + l_)*NDIM + h*NDH;
            #pragma unroll
            for (int dt=0; dt<4; dt++)
                ao[base + dt*16 + lo] = f2bf(o[qs][dt][r] * ivr);
        }
    }
}

extern "C" void kernel_launch(void* const* d_in, const int* in_sizes, int n_in,
                              void* d_out, int out_size, void* d_ws, size_t ws_size,
                              hipStream_t stream) {
    const float* x      = (const float*)d_in[0];
    const float* time_  = (const float*)d_in[1];
    const float* smask  = (const float*)d_in[2];
    const float* cycm   = (const float*)d_in[3];
    const float* gamma  = (const float*)d_in[4];
    const float* Wt     = (const float*)d_in[5];
    const float* bt     = (const float*)d_in[6];
    const float* Wq     = (const float*)d_in[7];
    const float* Wkv    = (const float*)d_in[8];
    const float* Wo     = (const float*)d_in[9];
    const float* rf     = (const float*)d_in[10];
    const int*   resi   = (const int*)d_in[11];
    const int*   chain  = (const int*)d_in[12];
    float* out = (float*)d_out;

    float*  ss     = (float*)d_ws;                   // 8192
    float*  cnts   = ss + 8192;                      // 16 (pad)
    float*  cosb   = cnts + 16;                      // 131072
    float*  sinb   = cosb + 131072;                  // 131072
    ushort* xc     = (ushort*)(sinb + 131072);       // 4096*1024
    ushort* wqkv   = xc + 4194304;                   // 3072*1024
    ushort* wo     = wqkv + 3145728;                 // 1024*1024
    ushort* qbuf   = wo + 1048576;                   // 4*16*1024*64
    ushort* kbuf   = qbuf + 4194304;
    ushort* vbuf   = kbuf + 4194304;
    ushort* vtb    = vbuf + 4194304;
    ushort* aob    = vtb + 4194304;

    hipLaunchKernelGGL(k_ss,      dim3(2048),    dim3(256), 0, stream, time_, Wt, bt, ss);
    hipLaunchKernelGGL(k_counts,  dim3(8),       dim3(256), 0, stream, chain, cycm, cnts);
    hipLaunchKernelGGL(k_angles,  dim3(512),     dim3(256), 0, stream, resi, chain, cycm, rf, cnts, cosb, sinb);
    hipLaunchKernelGGL(k_convall, dim3(4096),    dim3(256), 0, stream, Wq, Wkv, Wo, wqkv, wo);
    hipLaunchKernelGGL(k_lnmod,   dim3(4096),    dim3(256), 0, stream, x, smask, gamma, ss, xc);
    hipLaunchKernelGGL((k_mm<0>), dim3(24,32),   dim3(256), 0, stream, xc, wqkv, qbuf, kbuf, vbuf, (float*)nullptr, (const float*)nullptr);
    hipLaunchKernelGGL(k_rope,    dim3(8192),    dim3(256), 0, stream, qbuf, kbuf, cosb, sinb);
    hipLaunchKernelGGL(k_vt,      dim3(16,64),   dim3(256), 0, stream, vbuf, vtb);
    hipLaunchKernelGGL(k_fattn,   dim3(512),     dim3(256), 0, stream, qbuf, kbuf, vtb, smask, aob);
    hipLaunchKernelGGL((k_mm<1>), dim3(8,32),    dim3(256), 0, stream, aob, wo, (ushort*)nullptr, (ushort*)nullptr, (ushort*)nullptr, out, smask);
}

// Round 5
// 220.185 us; speedup vs baseline: 6.7250x; 1.0477x over previous
//
#include <hip/hip_runtime.h>
#include <hip/hip_bf16.h>
#include <math.h>

#define NB 4
#define NL 1024
#define NDIM 1024
#define NH 16
#define NDH 64
#define NEG_MAX (-3.402823466e38f)

typedef __attribute__((ext_vector_type(4))) float fx4;
typedef __attribute__((ext_vector_type(8))) short bh8;

__device__ __forceinline__ ushort f2bf(float f){
    __hip_bfloat16 h = __float2bfloat16(f);   // RNE; compiler fuses pairs to cvt_pk
    return *(ushort*)&h;
}
__device__ __forceinline__ float bf2f(ushort h){
    return __uint_as_float(((unsigned)h)<<16);
}
__device__ __forceinline__ void gload16(const void* g, void* l){
    __builtin_amdgcn_global_load_lds((const __attribute__((address_space(1))) void*)g,
                                     (__attribute__((address_space(3))) void*)l, 16, 0, 0);
}

// ================= pre1: ss (2048) | counts (8) | weight convert (4096) ==============
__global__ __launch_bounds__(256) void k_pre1(const float* __restrict__ time_, const float* __restrict__ Wt,
                                              const float* __restrict__ bt, float* __restrict__ ss,
                                              const int* __restrict__ chain, const float* __restrict__ cyc,
                                              float* __restrict__ counts,
                                              const float* __restrict__ Wq, const float* __restrict__ Wkv,
                                              const float* __restrict__ Wo,
                                              ushort* __restrict__ wqkv, ushort* __restrict__ wo){
    __shared__ float red[4];
    int bx = blockIdx.x, t = threadIdx.x;
    if (bx < 2048){
        // ---- ss = silu(time) @ Wt.T + bt ----
        int gw   = (bx*256 + t) >> 6;
        int lane = t & 63;
        int b = gw >> 11, j = gw & 2047;
        const float* a = time_ + b*NDIM;
        const float* w = Wt + (size_t)j*NDIM;
        float s = 0.f;
        #pragma unroll 4
        for (int i = lane; i < NDIM; i += 64){
            float v = a[i];
            s += (v / (1.f + __expf(-v))) * w[i];
        }
        #pragma unroll
        for (int off=32; off; off>>=1) s += __shfl_xor(s, off, 64);
        if (!lane) ss[gw] = s + bt[j];
    } else if (bx < 2056){
        // ---- counts[b][c] ----
        int cb = bx - 2048;
        int b = cb >> 1, c = cb & 1;
        float s = 0.f;
        for (int l = t; l < NL; l += 256)
            s += (chain[b*NL+l]==c) ? cyc[b*NL+l] : 0.f;
        #pragma unroll
        for (int off=32; off; off>>=1) s += __shfl_xor(s, off, 64);
        if (!(t & 63)) red[t>>6] = s;
        __syncthreads();
        if (!t) counts[cb] = red[0]+red[1]+red[2]+red[3];
    } else {
        // ---- weights f32->bf16: Wq|Wkv -> wqkv, Wo -> wo (4194304 elems) ----
        int i = ((bx-2056)*256 + t)*4;
        const float* src; ushort* dst;
        if (i < 3145728){
            dst = wqkv + i;
            src = (i < 1048576) ? (Wq + i) : (Wkv + (i - 1048576));
        } else {
            dst = wo + (i - 3145728);
            src = Wo + (i - 3145728);
        }
        fx4 v = *(const fx4*)src;
        ushort4 o; o.x=f2bf(v.x); o.y=f2bf(v.y); o.z=f2bf(v.z); o.w=f2bf(v.w);
        *(ushort4*)dst = o;
    }
}

// ================= pre2: angles (512) | layernorm+modulate (4096) ==============
__global__ __launch_bounds__(256) void k_pre2(const int* __restrict__ resi, const int* __restrict__ chain,
                                              const float* __restrict__ cyc, const float* __restrict__ rf,
                                              const float* __restrict__ counts,
                                              float* __restrict__ cosb, float* __restrict__ sinb,
                                              const float* __restrict__ x, const float* __restrict__ sm,
                                              const float* __restrict__ gamma, const float* __restrict__ ss,
                                              ushort* __restrict__ xc){
    __shared__ float r1[4], r2[4];
    int bx = blockIdx.x, t = threadIdx.x;
    if (bx < 512){
        int idx = bx*256 + t;                        // NB*NL*32
        int f  = idx & 31;
        int bl = idx >> 5;
        int b  = bl >> 10;
        float tt = (float)resi[bl];
        int   ci = chain[bl];
        float cm = cyc[bl];
        float ang;
        if (cm > 0.f) {
            float ring      = counts[b*2+ci] * cm;
            float ring_safe = fmaxf(ring, 1.f);
            float max_k     = fmaxf(floorf(ring_safe*0.5f), 1.f);
            float k_eff     = (max_k == 1.f) ? 1.f : (1.f + fmodf((float)f, max_k));
            float omega     = 6.28318530717958647692f * k_eff / ring_safe;
            ang = omega * tt;
        } else {
            ang = tt * rf[f] + (float)ci * rf[0];
        }
        cosb[idx] = cosf(ang);
        sinb[idx] = sinf(ang);
    } else {
        int row = bx - 512;                          // 0..4095
        int b   = row >> 10;
        float msk = sm[row];
        fx4 v = ((const fx4*)(x + (size_t)row*NDIM))[t];
        v.x*=msk; v.y*=msk; v.z*=msk; v.w*=msk;
        float s1 = v.x+v.y+v.z+v.w;
        float s2 = v.x*v.x + v.y*v.y + v.z*v.z + v.w*v.w;
        #pragma unroll
        for (int off=32; off; off>>=1){ s1 += __shfl_xor(s1,off,64); s2 += __shfl_xor(s2,off,64); }
        if (!(t & 63)){ r1[t>>6]=s1; r2[t>>6]=s2; }
        __syncthreads();
        s1 = r1[0]+r1[1]+r1[2]+r1[3];
        s2 = r2[0]+r2[1]+r2[2]+r2[3];
        float mu  = s1 * (1.f/NDIM);
        float var = s2 * (1.f/NDIM) - mu*mu;
        float rs  = rsqrtf(var + 1e-5f);
        const float* sc = ss + b*2048;
        fx4 g   = ((const fx4*)gamma)[t];
        fx4 scl = ((const fx4*)sc)[t];
        fx4 sh  = ((const fx4*)(sc+1024))[t];
        ushort4 ob;
        ob.x = f2bf((v.x-mu)*rs*g.x*(1.f+scl.x)+sh.x);
        ob.y = f2bf((v.y-mu)*rs*g.y*(1.f+scl.y)+sh.y);
        ob.z = f2bf((v.z-mu)*rs*g.z*(1.f+scl.z)+sh.z);
        ob.w = f2bf((v.w-mu)*rs*g.w*(1.f+scl.w)+sh.w);
        *(ushort4*)(xc + (size_t)row*NDIM + t*4) = ob;
    }
}

// ================= bf16 MFMA GEMM, 2-phase double-buffered staging =================
// MODE 0: N=3072, split q/k/v -> [B,H,L,DH] bf16. MODE 1: N=1024, f32 out * seq_mask.
template<int MODE>
__global__ __launch_bounds__(256) void k_mm(const ushort* __restrict__ A, const ushort* __restrict__ W,
                                            ushort* __restrict__ qo, ushort* __restrict__ ko,
                                            ushort* __restrict__ vo,
                                            float* __restrict__ outf, const float* __restrict__ smask){
    __shared__ ushort As[2][128*32];
    __shared__ ushort Bs[2][128*32];
    int t = threadIdx.x, l = t&63, w = t>>6;
    int lo = l&15, hi = l>>4;
    // bijective XCD-chunked swizzle (nwg % 8 == 0)
    const int nbx = (MODE==0) ? 24 : 8;
    const int nwg = (MODE==0) ? 768 : 256;
    int lin = blockIdx.y*nbx + blockIdx.x;
    int swz = (lin & 7)*(nwg>>3) + (lin>>3);
    int m0 = (swz/nbx)*128, n0 = (swz%nbx)*128;
    int wm = (w>>1)*64, wn = (w&1)*64;
    fx4 acc[4][4];
    #pragma unroll
    for (int i=0;i<4;i++)
        #pragma unroll
        for (int j=0;j<4;j++) acc[i][j] = (fx4){0.f,0.f,0.f,0.f};
    const char* Ab = (const char*)A;
    const char* Wb = (const char*)W;

    #define MMSTAGE(bb, k0) { \
        _Pragma("unroll") \
        for (int e=0;e<2;e++){ \
            int c = t + e*256; \
            int row = c>>2, cw = c&3; \
            gload16(Ab + (size_t)(m0+row)*2048 + (k0)*2 + cw*16, (char*)As[bb] + c*16); \
            gload16(Wb + (size_t)(n0+row)*2048 + (k0)*2 + cw*16, (char*)Bs[bb] + c*16); \
        } }

    MMSTAGE(0, 0);
    __syncthreads();
    for (int kt=0; kt<32; kt++){
        int cur = kt & 1;
        if (kt < 31) MMSTAGE(cur^1, (kt+1)*32);      // issue next-tile loads early
        bh8 af[4], bf[4];
        #pragma unroll
        for (int i=0;i<4;i++) af[i] = *(const bh8*)(&As[cur][0] + (wm + i*16 + lo)*32 + hi*8);
        #pragma unroll
        for (int j=0;j<4;j++) bf[j] = *(const bh8*)(&Bs[cur][0] + (wn + j*16 + lo)*32 + hi*8);
        #pragma unroll
        for (int i=0;i<4;i++)
            #pragma unroll
            for (int j=0;j<4;j++)
                acc[i][j] = __builtin_amdgcn_mfma_f32_16x16x32_bf16(af[i], bf[j], acc[i][j], 0, 0, 0);
        __syncthreads();                              // drains vmcnt too (stage complete)
    }
    #undef MMSTAGE

    #pragma unroll
    for (int i=0;i<4;i++){
        #pragma unroll
        for (int r=0;r<4;r++){
            int m = m0 + wm + i*16 + hi*4 + r;
            int b_ = m>>10, l_ = m&1023;
            #pragma unroll
            for (int j=0;j<4;j++){
                int n = n0 + wn + j*16 + lo;
                float val = acc[i][j][r];
                if (MODE==0){
                    int nn = n & 1023;
                    int h_ = nn>>6, d_ = nn&63;
                    size_t off = (size_t)((b_*NH + h_)*NL + l_)*NDH + d_;
                    if (n < 1024)      qo[off] = f2bf(val);
                    else if (n < 2048) ko[off] = f2bf(val);
                    else               vo[off] = f2bf(val);
                } else {
                    outf[(size_t)m*NDIM + n] = val * smask[m];
                }
            }
        }
    }
}

// ================= mid: RoPE (8192) | V-transpose (1024) ==============
__global__ __launch_bounds__(256) void k_mid(ushort* __restrict__ q, ushort* __restrict__ k,
                                             const float* __restrict__ cosb, const float* __restrict__ sinb,
                                             const ushort* __restrict__ v, ushort* __restrict__ vt){
    __shared__ ushort tile[64][65];
    int bx = blockIdx.x, t = threadIdx.x;
    if (bx < 8192){
        int idx = bx*256 + t;                        // NB*NH*NL*32
        int f   = idx & 31;
        int bhl = idx >> 5;
        int l   = bhl & 1023;
        int b   = bhl >> 14;
        int ca  = ((b<<10)|l)*32 + f;
        float c = cosb[ca], s = sinb[ca];
        const float QS = 0.18033688011112042f;       // 0.125 * log2(e)
        unsigned qp = ((const unsigned*)q)[idx];
        unsigned kp = ((const unsigned*)k)[idx];
        float qx = bf2f((ushort)(qp&0xffffu)), qy = bf2f((ushort)(qp>>16));
        float kx = bf2f((ushort)(kp&0xffffu)), ky = bf2f((ushort)(kp>>16));
        float q0 = (qx*c - qy*s)*QS, q1 = (qy*c + qx*s)*QS;
        float k0 = kx*c - ky*s,      k1 = ky*c + kx*s;
        ((unsigned*)q)[idx] = (unsigned)f2bf(q0) | ((unsigned)f2bf(q1)<<16);
        ((unsigned*)k)[idx] = (unsigned)f2bf(k0) | ((unsigned)f2bf(k1)<<16);
    } else {
        int vb = bx - 8192;
        int bh = vb >> 4, l0 = (vb & 15)*64;
        #pragma unroll
        for (int e=0;e<2;e++){
            int c = t + e*256;
            int row = c>>3, cw = c&7;
            bh8 d = *(const bh8*)(v + ((size_t)bh*NL + l0 + row)*NDH + cw*8);
            #pragma unroll
            for (int x2=0;x2<8;x2++) tile[row][cw*8+x2] = (ushort)d[x2];
        }
        __syncthreads();
        #pragma unroll
        for (int e=0;e<2;e++){
            int c = t + e*256;
            int drow = c>>3, cw = c&7;
            bh8 o;
            #pragma unroll
            for (int x2=0;x2<8;x2++) o[x2] = (short)tile[cw*8+x2][drow];
            *(bh8*)(vt + ((size_t)bh*NDH + drow)*NL + l0 + cw*8) = o;
        }
    }
}

// ================= MFMA flash attention v4 =================
// Swapped QK^T (lane-local rows), QBLK=128, KVB=64, dbuf global_load_lds,
// XCD-chunked grid, defer-max (T13), setprio (T5), b64 P-writes.
__global__ __launch_bounds__(256) void k_fattn(const ushort* __restrict__ qb, const ushort* __restrict__ kb,
                                               const ushort* __restrict__ vt, const float* __restrict__ smask,
                                               ushort* __restrict__ ao){
    __shared__ ushort Ks[2][64*64];     // [kv][dh], xor-swizzled rows
    __shared__ ushort Vs[2][64*64];     // [dh][kv], xor-swizzled rows
    __shared__ ushort Ps[4][32*64];     // per-wave P [q][kv], xor-swizzled rows
    int t = threadIdx.x, l = t&63, w = t>>6;
    int lo = l&15, hi = l>>4;
    int logical = (blockIdx.x & 7)*64 + (blockIdx.x >> 3);
    int bh = logical >> 3;
    int qt = logical & 7;
    int b = bh>>4, h = bh&15;
    int q0 = qt*128;
    int swzq = (lo&7)<<4;

    bh8 aq[2][2];
    #pragma unroll
    for (int qs=0; qs<2; qs++){
        const ushort* qrow = qb + ((size_t)bh*NL + q0 + w*32 + qs*16 + lo)*NDH;
        aq[qs][0] = *(const bh8*)(qrow + hi*8);
        aq[qs][1] = *(const bh8*)(qrow + 32 + hi*8);
    }
    const float* mrow = smask + b*NL;

    fx4 o[2][4];
    float mrun[2], lrun[2];
    #pragma unroll
    for (int qs=0; qs<2; qs++){
        mrun[qs]=NEG_MAX; lrun[qs]=0.f;
        #pragma unroll
        for (int dt=0; dt<4; dt++) o[qs][dt] = (fx4){0.f,0.f,0.f,0.f};
    }

    const char* kbase = (const char*)(kb + (size_t)bh*NL*NDH);
    const char* vbase = (const char*)(vt + (size_t)bh*NDH*NL);

    #define STAGE(bb, jt) { \
        int j0s = (jt)*64; \
        _Pragma("unroll") \
        for (int e=0;e<2;e++){ \
            int c = t + e*256; \
            int row = c>>3, cw = c&7; \
            int lc = cw ^ (row&7); \
            gload16(kbase + (size_t)(j0s+row)*128 + lc*16, (char*)Ks[bb] + c*16); \
        } \
        _Pragma("unroll") \
        for (int e=0;e<2;e++){ \
            int c = t + e*256; \
            int row = c>>3, cw = c&7; \
            int lc = cw ^ (row&7); \
            gload16(vbase + (size_t)row*2048 + j0s*2 + lc*16, (char*)Vs[bb] + c*16); \
        } }

    STAGE(0, 0);
    __syncthreads();

    for (int tt=0; tt<16; ++tt){
        int cur = tt & 1;
        if (tt < 15) STAGE(cur^1, tt+1);
        int j0 = tt*64;
        const char* KsB = (const char*)Ks[cur];
        const char* VsB = (const char*)Vs[cur];
        char* PsB = (char*)&Ps[w][0];

        // ---- S^T = K Q^T ----
        bh8 kf[4][2];
        #pragma unroll
        for (int j=0;j<4;j++){
            int row = j*16 + lo;
            int swz = (row&7)<<4;
            kf[j][0] = *(const bh8*)(KsB + row*128 + ((hi*16) ^ swz));
            kf[j][1] = *(const bh8*)(KsB + row*128 + ((64 + hi*16) ^ swz));
        }
        fx4 s[2][4];
        __builtin_amdgcn_s_setprio(1);
        #pragma unroll
        for (int qs=0; qs<2; qs++)
            #pragma unroll
            for (int j=0;j<4;j++){
                fx4 z = (fx4){0.f,0.f,0.f,0.f};
                z = __builtin_amdgcn_mfma_f32_16x16x32_bf16(kf[j][0], aq[qs][0], z, 0,0,0);
                z = __builtin_amdgcn_mfma_f32_16x16x32_bf16(kf[j][1], aq[qs][1], z, 0,0,0);
                s[qs][j] = z;
            }
        __builtin_amdgcn_s_setprio(0);
        // ---- mask ----
        #pragma unroll
        for (int j=0;j<4;j++){
            float4 mv = *(const float4*)(mrow + j0 + j*16 + hi*4);
            s[0][j][0] = mv.x>0.f ? s[0][j][0] : NEG_MAX;  s[1][j][0] = mv.x>0.f ? s[1][j][0] : NEG_MAX;
            s[0][j][1] = mv.y>0.f ? s[0][j][1] : NEG_MAX;  s[1][j][1] = mv.y>0.f ? s[1][j][1] : NEG_MAX;
            s[0][j][2] = mv.z>0.f ? s[0][j][2] : NEG_MAX;  s[1][j][2] = mv.z>0.f ? s[1][j][2] : NEG_MAX;
            s[0][j][3] = mv.w>0.f ? s[0][j][3] : NEG_MAX;  s[1][j][3] = mv.w>0.f ? s[1][j][3] : NEG_MAX;
        }

        // ---- online softmax with defer-max (exp2 domain, THR=8) ----
        #pragma unroll
        for (int qs=0; qs<2; qs++){
            float m0 = fmaxf(fmaxf(s[qs][0][0], s[qs][0][1]), s[qs][0][2]);
            float m1 = fmaxf(fmaxf(s[qs][0][3], s[qs][1][0]), s[qs][1][1]);
            float m2 = fmaxf(fmaxf(s[qs][1][2], s[qs][1][3]), s[qs][2][0]);
            float m3 = fmaxf(fmaxf(s[qs][2][1], s[qs][2][2]), s[qs][2][3]);
            float m4 = fmaxf(fmaxf(s[qs][3][0], s[qs][3][1]), s[qs][3][2]);
            float mt = fmaxf(fmaxf(fmaxf(m0,m1),m2), fmaxf(fmaxf(m3,m4), s[qs][3][3]));
            mt = fmaxf(mt, __shfl_xor(mt, 16));
            mt = fmaxf(mt, __shfl_xor(mt, 32));
            if (__any(mt > mrun[qs] + 8.f)){          // rescale path (rare after tile 0)
                float mnew = fmaxf(mrun[qs], mt);
                float cc = __builtin_amdgcn_exp2f(mrun[qs] - mnew);
                lrun[qs] *= cc;
                mrun[qs] = mnew;
                #pragma unroll
                for (int r=0;r<4;r++){
                    float ccr = __shfl(cc, hi*4 + r);
                    #pragma unroll
                    for (int dt=0; dt<4; dt++) o[qs][dt][r] *= ccr;
                }
            }
            float p[4][4];
            #pragma unroll
            for (int j=0;j<4;j++)
                #pragma unroll
                for (int r=0;r<4;r++) p[j][r] = __builtin_amdgcn_exp2f(s[qs][j][r] - mrun[qs]);
            float r0 = (p[0][0]+p[0][1]) + (p[0][2]+p[0][3]);
            float r1 = (p[1][0]+p[1][1]) + (p[1][2]+p[1][3]);
            float r2 = (p[2][0]+p[2][1]) + (p[2][2]+p[2][3]);
            float r3 = (p[3][0]+p[3][1]) + (p[3][2]+p[3][3]);
            float rs = (r0+r1)+(r2+r3);
            rs += __shfl_xor(rs, 16);
            rs += __shfl_xor(rs, 32);
            lrun[qs] += rs;
            // pack P pairs -> wave-private swizzled LDS (b64 writes)
            #pragma unroll
            for (int j=0;j<4;j++){
                uint2 wd;
                wd.x = (unsigned)f2bf(p[j][0]) | ((unsigned)f2bf(p[j][1])<<16);
                wd.y = (unsigned)f2bf(p[j][2]) | ((unsigned)f2bf(p[j][3])<<16);
                *(uint2*)(PsB + (qs*16+lo)*128 + ((j*32 + hi*8) ^ swzq)) = wd;
            }
        }

        // ---- P A-frags + O += P V ----
        bh8 ap[2][2];
        #pragma unroll
        for (int qs=0; qs<2; qs++){
            ap[qs][0] = *(const bh8*)(PsB + (qs*16+lo)*128 + ((hi*16) ^ swzq));
            ap[qs][1] = *(const bh8*)(PsB + (qs*16+lo)*128 + ((64 + hi*16) ^ swzq));
        }
        __builtin_amdgcn_s_setprio(1);
        #pragma unroll
        for (int dt=0; dt<4; dt++){
            int row = dt*16 + lo;
            int swz = (row&7)<<4;
            bh8 bv0 = *(const bh8*)(VsB + row*128 + ((hi*16) ^ swz));
            bh8 bv1 = *(const bh8*)(VsB + row*128 + ((64 + hi*16) ^ swz));
            o[0][dt] = __builtin_amdgcn_mfma_f32_16x16x32_bf16(ap[0][0], bv0, o[0][dt], 0,0,0);
            o[0][dt] = __builtin_amdgcn_mfma_f32_16x16x32_bf16(ap[0][1], bv1, o[0][dt], 0,0,0);
            o[1][dt] = __builtin_amdgcn_mfma_f32_16x16x32_bf16(ap[1][0], bv0, o[1][dt], 0,0,0);
            o[1][dt] = __builtin_amdgcn_mfma_f32_16x16x32_bf16(ap[1][1], bv1, o[1][dt], 0,0,0);
        }
        __builtin_amdgcn_s_setprio(0);
        __syncthreads();
    }
    #undef STAGE

    // ---- epilogue ----
    #pragma unroll
    for (int qs=0; qs<2; qs++){
        float inv = 1.f / lrun[qs];
        #pragma unroll
        for (int r=0;r<4;r++){
            float ivr = __shfl(inv, hi*4 + r);
            int l_ = q0 + w*32 + qs*16 + hi*4 + r;
            size_t base = ((size_t)b*NL + l_)*NDIM + h*NDH;
            #pragma unroll
            for (int dt=0; dt<4; dt++)
                ao[base + dt*16 + lo] = f2bf(o[qs][dt][r] * ivr);
        }
    }
}

extern "C" void kernel_launch(void* const* d_in, const int* in_sizes, int n_in,
                              void* d_out, int out_size, void* d_ws, size_t ws_size,
                              hipStream_t stream) {
    const float* x      = (const float*)d_in[0];
    const float* time_  = (const float*)d_in[1];
    const float* smask  = (const float*)d_in[2];
    const float* cycm   = (const float*)d_in[3];
    const float* gamma  = (const float*)d_in[4];
    const float* Wt     = (const float*)d_in[5];
    const float* bt     = (const float*)d_in[6];
    const float* Wq     = (const float*)d_in[7];
    const float* Wkv    = (const float*)d_in[8];
    const float* Wo     = (const float*)d_in[9];
    const float* rf     = (const float*)d_in[10];
    const int*   resi   = (const int*)d_in[11];
    const int*   chain  = (const int*)d_in[12];
    float* out = (float*)d_out;

    float*  ss     = (float*)d_ws;                   // 8192
    float*  cnts   = ss + 8192;                      // 16 (pad)
    float*  cosb   = cnts + 16;                      // 131072
    float*  sinb   = cosb + 131072;                  // 131072
    ushort* xc     = (ushort*)(sinb + 131072);       // 4096*1024
    ushort* wqkv   = xc + 4194304;                   // 3072*1024
    ushort* wo     = wqkv + 3145728;                 // 1024*1024
    ushort* qbuf   = wo + 1048576;                   // 4*16*1024*64
    ushort* kbuf   = qbuf + 4194304;
    ushort* vbuf   = kbuf + 4194304;
    ushort* vtb    = vbuf + 4194304;
    ushort* aob    = vtb + 4194304;

    hipLaunchKernelGGL(k_pre1,   dim3(6152),   dim3(256), 0, stream,
                       time_, Wt, bt, ss, chain, cycm, cnts, Wq, Wkv, Wo, wqkv, wo);
    hipLaunchKernelGGL(k_pre2,   dim3(4608),   dim3(256), 0, stream,
                       resi, chain, cycm, rf, cnts, cosb, sinb, x, smask, gamma, ss, xc);
    hipLaunchKernelGGL((k_mm<0>), dim3(24,32), dim3(256), 0, stream,
                       xc, wqkv, qbuf, kbuf, vbuf, (float*)nullptr, (const float*)nullptr);
    hipLaunchKernelGGL(k_mid,    dim3(9216),   dim3(256), 0, stream,
                       qbuf, kbuf, cosb, sinb, vbuf, vtb);
    hipLaunchKernelGGL(k_fattn,  dim3(512),    dim3(256), 0, stream,
                       qbuf, kbuf, vtb, smask, aob);
    hipLaunchKernelGGL((k_mm<1>), dim3(8,32),  dim3(256), 0, stream,
                       aob, wo, (ushort*)nullptr, (ushort*)nullptr, (ushort*)nullptr, out, smask);
}

// Round 7
// 212.752 us; speedup vs baseline: 6.9599x; 1.0349x over previous
//
#include <hip/hip_runtime.h>
#include <hip/hip_bf16.h>
#include <math.h>

#define NB 4
#define NL 1024
#define NDIM 1024
#define NH 16
#define NDH 64
#define NEG_MAX (-3.402823466e38f)

typedef __attribute__((ext_vector_type(4))) float fx4;
typedef __attribute__((ext_vector_type(8))) short bh8;

__device__ __forceinline__ ushort f2bf(float f){
    __hip_bfloat16 h = __float2bfloat16(f);   // RNE; compiler fuses pairs to cvt_pk
    return *(ushort*)&h;
}
__device__ __forceinline__ float bf2f(ushort h){
    return __uint_as_float(((unsigned)h)<<16);
}
__device__ __forceinline__ void gload16(const void* g, void* l){
    __builtin_amdgcn_global_load_lds((const __attribute__((address_space(1))) void*)g,
                                     (__attribute__((address_space(3))) void*)l, 16, 0, 0);
}

// ================= pre1: ss (2048) | counts (8) | weight convert (4096) ==============
__global__ __launch_bounds__(256) void k_pre1(const float* __restrict__ time_, const float* __restrict__ Wt,
                                              const float* __restrict__ bt, float* __restrict__ ss,
                                              const int* __restrict__ chain, const float* __restrict__ cyc,
                                              float* __restrict__ counts,
                                              const float* __restrict__ Wq, const float* __restrict__ Wkv,
                                              const float* __restrict__ Wo,
                                              ushort* __restrict__ wqkv, ushort* __restrict__ wo){
    __shared__ float red[4];
    int bx = blockIdx.x, t = threadIdx.x;
    if (bx < 2048){
        int gw   = (bx*256 + t) >> 6;
        int lane = t & 63;
        int b = gw >> 11, j = gw & 2047;
        const float* a = time_ + b*NDIM;
        const float* w = Wt + (size_t)j*NDIM;
        float s = 0.f;
        #pragma unroll 4
        for (int i = lane; i < NDIM; i += 64){
            float v = a[i];
            s += (v / (1.f + __expf(-v))) * w[i];
        }
        #pragma unroll
        for (int off=32; off; off>>=1) s += __shfl_xor(s, off, 64);
        if (!lane) ss[gw] = s + bt[j];
    } else if (bx < 2056){
        int cb = bx - 2048;
        int b = cb >> 1, c = cb & 1;
        float s = 0.f;
        for (int l = t; l < NL; l += 256)
            s += (chain[b*NL+l]==c) ? cyc[b*NL+l] : 0.f;
        #pragma unroll
        for (int off=32; off; off>>=1) s += __shfl_xor(s, off, 64);
        if (!(t & 63)) red[t>>6] = s;
        __syncthreads();
        if (!t) counts[cb] = red[0]+red[1]+red[2]+red[3];
    } else {
        int i = ((bx-2056)*256 + t)*4;   // 4096 blocks -> 4194304 elems exactly
        const float* src; ushort* dst;
        if (i < 3145728){
            dst = wqkv + i;
            src = (i < 1048576) ? (Wq + i) : (Wkv + (i - 1048576));
        } else {
            dst = wo + (i - 3145728);
            src = Wo + (i - 3145728);
        }
        fx4 v = *(const fx4*)src;
        ushort4 o; o.x=f2bf(v.x); o.y=f2bf(v.y); o.z=f2bf(v.z); o.w=f2bf(v.w);
        *(ushort4*)dst = o;
    }
}

// ================= pre2: angles->cs float2 (512) | layernorm+modulate (4096) ==============
__global__ __launch_bounds__(256) void k_pre2(const int* __restrict__ resi, const int* __restrict__ chain,
                                              const float* __restrict__ cyc, const float* __restrict__ rf,
                                              const float* __restrict__ counts,
                                              float2* __restrict__ cs,
                                              const float* __restrict__ x, const float* __restrict__ sm,
                                              const float* __restrict__ gamma, const float* __restrict__ ss,
                                              ushort* __restrict__ xc){
    __shared__ float r1[4], r2[4];
    int bx = blockIdx.x, t = threadIdx.x;
    if (bx < 512){
        int idx = bx*256 + t;                        // NB*NL*32
        int f  = idx & 31;
        int bl = idx >> 5;
        int b  = bl >> 10;
        float tt = (float)resi[bl];
        int   ci = chain[bl];
        float cm = cyc[bl];
        float ang;
        if (cm > 0.f) {
            float ring      = counts[b*2+ci] * cm;
            float ring_safe = fmaxf(ring, 1.f);
            float max_k     = fmaxf(floorf(ring_safe*0.5f), 1.f);
            float k_eff     = (max_k == 1.f) ? 1.f : (1.f + fmodf((float)f, max_k));
            float omega     = 6.28318530717958647692f * k_eff / ring_safe;
            ang = omega * tt;
        } else {
            ang = tt * rf[f] + (float)ci * rf[0];
        }
        cs[idx] = make_float2(cosf(ang), sinf(ang));
    } else {
        int row = bx - 512;                          // 0..4095
        int b   = row >> 10;
        float msk = sm[row];
        fx4 v = ((const fx4*)(x + (size_t)row*NDIM))[t];
        v.x*=msk; v.y*=msk; v.z*=msk; v.w*=msk;
        float s1 = v.x+v.y+v.z+v.w;
        float s2 = v.x*v.x + v.y*v.y + v.z*v.z + v.w*v.w;
        #pragma unroll
        for (int off=32; off; off>>=1){ s1 += __shfl_xor(s1,off,64); s2 += __shfl_xor(s2,off,64); }
        if (!(t & 63)){ r1[t>>6]=s1; r2[t>>6]=s2; }
        __syncthreads();
        s1 = r1[0]+r1[1]+r1[2]+r1[3];
        s2 = r2[0]+r2[1]+r2[2]+r2[3];
        float mu  = s1 * (1.f/NDIM);
        float var = s2 * (1.f/NDIM) - mu*mu;
        float rs  = rsqrtf(var + 1e-5f);
        const float* sc = ss + b*2048;
        fx4 g   = ((const fx4*)gamma)[t];
        fx4 scl = ((const fx4*)sc)[t];
        fx4 sh  = ((const fx4*)(sc+1024))[t];
        ushort4 ob;
        ob.x = f2bf((v.x-mu)*rs*g.x*(1.f+scl.x)+sh.x);
        ob.y = f2bf((v.y-mu)*rs*g.y*(1.f+scl.y)+sh.y);
        ob.z = f2bf((v.z-mu)*rs*g.z*(1.f+scl.z)+sh.z);
        ob.w = f2bf((v.w-mu)*rs*g.w*(1.f+scl.w)+sh.w);
        *(ushort4*)(xc + (size_t)row*NDIM + t*4) = ob;
    }
}

// ================= bf16 MFMA GEMM, counted-vmcnt 2-barrier loop =================
// MODE 0: N=3072. Epilogue: q/k -> RoPE fused, [B,H,L,DH]; v -> transposed [B,H,DH,L] via LDS.
// MODE 1: N=1024, f32 out * seq_mask.
template<int MODE>
__global__ __launch_bounds__(256) void k_mm(const ushort* __restrict__ A, const ushort* __restrict__ W,
                                            ushort* __restrict__ qo, ushort* __restrict__ ko,
                                            ushort* __restrict__ vo,
                                            float* __restrict__ outf, const float* __restrict__ smask,
                                            const float2* __restrict__ cs){
    union SMem {
        ushort stage[2][2][128*32];   // [mat][buf]
        ushort tx[64][136];           // V-transpose tile (odd stride -> bank-spread)
    };
    __shared__ SMem smem;
    int t = threadIdx.x, l = t&63, w = t>>6;
    int lo = l&15, hi = l>>4;
    const int nbx = (MODE==0) ? 24 : 8;
    const int nwg = (MODE==0) ? 768 : 256;
    int lin = blockIdx.y*nbx + blockIdx.x;
    int swz = (lin & 7)*(nwg>>3) + (lin>>3);     // bijective (nwg%8==0)
    int m0 = (swz/nbx)*128, n0 = (swz%nbx)*128;
    int wm = (w>>1)*64, wn = (w&1)*64;
    fx4 acc[4][4];
    #pragma unroll
    for (int i=0;i<4;i++)
        #pragma unroll
        for (int j=0;j<4;j++) acc[i][j] = (fx4){0.f,0.f,0.f,0.f};
    const char* Ab = (const char*)A;
    const char* Wb = (const char*)W;

    #define MMSTAGE(bb, k0) { \
        _Pragma("unroll") \
        for (int e=0;e<2;e++){ \
            int c = t + e*256; \
            int row = c>>2, cw = c&3; \
            gload16(Ab + (size_t)(m0+row)*2048 + (size_t)(k0)*2 + cw*16, (char*)smem.stage[0][bb] + c*16); \
            gload16(Wb + (size_t)(n0+row)*2048 + (size_t)(k0)*2 + cw*16, (char*)smem.stage[1][bb] + c*16); \
        } }

    MMSTAGE(0, 0);
    asm volatile("s_waitcnt vmcnt(0)" ::: "memory");
    __syncthreads();
    for (int kt=0; kt<32; kt++){
        int cur = kt & 1;
        MMSTAGE(cur^1, ((kt+1)&31)*32);            // prefetch (wraps harmlessly at kt=31)
        asm volatile("s_waitcnt vmcnt(4)" ::: "memory");   // cur staged; next stays in flight
        __builtin_amdgcn_s_barrier();
        __builtin_amdgcn_sched_barrier(0);
        bh8 af[4], bf[4];
        #pragma unroll
        for (int i=0;i<4;i++) af[i] = *(const bh8*)(&smem.stage[0][cur][0] + (wm + i*16 + lo)*32 + hi*8);
        #pragma unroll
        for (int j=0;j<4;j++) bf[j] = *(const bh8*)(&smem.stage[1][cur][0] + (wn + j*16 + lo)*32 + hi*8);
        #pragma unroll
        for (int i=0;i<4;i++)
            #pragma unroll
            for (int j=0;j<4;j++)
                acc[i][j] = __builtin_amdgcn_mfma_f32_16x16x32_bf16(af[i], bf[j], acc[i][j], 0, 0, 0);
        __builtin_amdgcn_s_barrier();              // reads done before next prefetch overwrites
    }
    #undef MMSTAGE

    if (MODE==0){
        if (n0 < 2048){
            // ---- q/k epilogue with fused RoPE (from f32 acc; interleaved pairs) ----
            const float qsc = (n0 < 1024) ? 0.18033688011112042f : 1.0f;  // q: DH^-0.5 * log2(e)
            ushort* dst0 = (n0 < 1024) ? qo : ko;
            #pragma unroll
            for (int i=0;i<4;i++){
                #pragma unroll
                for (int r=0;r<4;r++){
                    int m = m0 + wm + i*16 + hi*4 + r;      // m == b*1024 + l
                    int b_ = m>>10, l_ = m&1023;
                    const float2* csrow = cs + (size_t)m*32;
                    #pragma unroll
                    for (int j=0;j<4;j++){
                        int nn = (n0 + wn + j*16 + lo) & 1023;
                        int h_ = nn>>6, d_ = nn&63;
                        float2 cspair = csrow[d_>>1];
                        float val = acc[i][j][r];
                        float partner = __shfl_xor(val, 1);
                        float rot = (lo&1) ? fmaf(val, cspair.x,  partner*cspair.y)
                                           : fmaf(val, cspair.x, -partner*cspair.y);
                        size_t off = ((size_t)(b_*NH + h_)*NL + l_)*NDH + d_;
                        dst0[off] = f2bf(rot * qsc);
                    }
                }
            }
        } else {
            // ---- v epilogue: write transposed vt[bh][dh][l] via LDS half-tiles ----
            asm volatile("s_waitcnt vmcnt(0)" ::: "memory");  // drain wrap-prefetch before LDS reuse
            __syncthreads();
            int b_ = m0>>10;
            #pragma unroll
            for (int half=0; half<2; half++){
                if ((w&1) == half){
                    #pragma unroll
                    for (int i=0;i<4;i++)
                        #pragma unroll
                        for (int r=0;r<4;r++){
                            int ml = wm + i*16 + hi*4 + r;
                            #pragma unroll
                            for (int j=0;j<4;j++){
                                int nl = (wn + j*16 + lo) & 63;
                                smem.tx[nl][ml] = f2bf(acc[i][j][r]);
                            }
                        }
                }
                __syncthreads();
                int rr = t>>2, qq = t&3;
                int ng = (n0 - 2048) + half*64 + rr;
                int h_ = ng>>6, d_ = ng&63;
                ushort* dst = vo + ((size_t)((b_*NH + h_)*NDH + d_))*NL + (m0 & 1023) + qq*32;
                #pragma unroll
                for (int c=0;c<4;c++)
                    *(bh8*)(dst + c*8) = *(const bh8*)(&smem.tx[rr][qq*32 + c*8]);
                __syncthreads();
            }
        }
    } else {
        #pragma unroll
        for (int i=0;i<4;i++){
            #pragma unroll
            for (int r=0;r<4;r++){
                int m = m0 + wm + i*16 + hi*4 + r;
                float msk = smask[m];
                #pragma unroll
                for (int j=0;j<4;j++){
                    int n = n0 + wn + j*16 + lo;
                    outf[(size_t)m*NDIM + n] = acc[i][j][r] * msk;
                }
            }
        }
    }
}

// ================= MFMA flash attention v5b =================
// Swapped QK^T, QBLK=128, KVB=64, counted-vmcnt(4) 2-barrier pipeline,
// seq_mask in LDS (lgkm path, no vmcnt entanglement), XCD-chunked grid,
// defer-max, setprio, Ps stride 144B.
__global__ __launch_bounds__(256) void k_fattn(const ushort* __restrict__ qb, const ushort* __restrict__ kb,
                                               const ushort* __restrict__ vt, const float* __restrict__ smask,
                                               ushort* __restrict__ ao){
    __shared__ ushort Ks[2][64*64];     // [kv][dh], xor-swizzled rows
    __shared__ ushort Vs[2][64*64];     // [dh][kv], xor-swizzled rows
    __shared__ ushort Ps[4][32*72];     // per-wave P, 144B row stride
    __shared__ float  Ms[1024];         // seq_mask row for this b
    int t = threadIdx.x, l = t&63, w = t>>6;
    int lo = l&15, hi = l>>4;
    int logical = (blockIdx.x & 7)*64 + (blockIdx.x >> 3);
    int bh = logical >> 3;
    int qt = logical & 7;
    int b = bh>>4, h = bh&15;
    int q0 = qt*128;
    int swzq = (lo&7)<<4;

    bh8 aq[2][2];
    #pragma unroll
    for (int qs=0; qs<2; qs++){
        const ushort* qrow = qb + ((size_t)bh*NL + q0 + w*32 + qs*16 + lo)*NDH;
        aq[qs][0] = *(const bh8*)(qrow + hi*8);
        aq[qs][1] = *(const bh8*)(qrow + 32 + hi*8);
    }
    const float* mrow = smask + b*NL;
    gload16((const char*)mrow + t*16, (char*)Ms + t*16);   // 256*16B = 4KB mask row

    fx4 o[2][4];
    float mrun[2], lrun[2];
    #pragma unroll
    for (int qs=0; qs<2; qs++){
        mrun[qs]=NEG_MAX; lrun[qs]=0.f;
        #pragma unroll
        for (int dt=0; dt<4; dt++) o[qs][dt] = (fx4){0.f,0.f,0.f,0.f};
    }

    const char* kbase = (const char*)(kb + (size_t)bh*NL*NDH);
    const char* vbase = (const char*)(vt + (size_t)bh*NDH*NL);

    #define STAGE(bb, jt) { \
        int j0s = (jt)*64; \
        _Pragma("unroll") \
        for (int e=0;e<2;e++){ \
            int c = t + e*256; \
            int row = c>>3, cw = c&7; \
            int lc = cw ^ (row&7); \
            gload16(kbase + (size_t)(j0s+row)*128 + lc*16, (char*)Ks[bb] + c*16); \
        } \
        _Pragma("unroll") \
        for (int e=0;e<2;e++){ \
            int c = t + e*256; \
            int row = c>>3, cw = c&7; \
            int lc = cw ^ (row&7); \
            gload16(vbase + (size_t)row*2048 + j0s*2 + lc*16, (char*)Vs[bb] + c*16); \
        } }

    STAGE(0, 0);
    asm volatile("s_waitcnt vmcnt(0)" ::: "memory");
    __syncthreads();

    for (int tt=0; tt<16; ++tt){
        int cur = tt & 1;
        STAGE(cur^1, (tt+1)&15);                   // prefetch (wraps harmlessly)
        asm volatile("s_waitcnt vmcnt(4)" ::: "memory");  // cur staged; next 4 stay in flight
        __builtin_amdgcn_s_barrier();
        __builtin_amdgcn_sched_barrier(0);
        int j0 = tt*64;

        const char* KsB = (const char*)Ks[cur];
        const char* VsB = (const char*)Vs[cur];
        char* PsB = (char*)&Ps[w][0];

        // ---- S^T = K Q^T ----
        bh8 kf[4][2];
        #pragma unroll
        for (int j=0;j<4;j++){
            int row = j*16 + lo;
            int kswz = (row&7)<<4;
            kf[j][0] = *(const bh8*)(KsB + row*128 + ((hi*16) ^ kswz));
            kf[j][1] = *(const bh8*)(KsB + row*128 + ((64 + hi*16) ^ kswz));
        }
        fx4 s[2][4];
        __builtin_amdgcn_s_setprio(1);
        #pragma unroll
        for (int qs=0; qs<2; qs++)
            #pragma unroll
            for (int j=0;j<4;j++){
                fx4 z = (fx4){0.f,0.f,0.f,0.f};
                z = __builtin_amdgcn_mfma_f32_16x16x32_bf16(kf[j][0], aq[qs][0], z, 0,0,0);
                z = __builtin_amdgcn_mfma_f32_16x16x32_bf16(kf[j][1], aq[qs][1], z, 0,0,0);
                s[qs][j] = z;
            }
        __builtin_amdgcn_s_setprio(0);
        // ---- mask (from LDS; 16-lane broadcast reads, conflict-free) ----
        #pragma unroll
        for (int j=0;j<4;j++){
            float4 mv = *(const float4*)(&Ms[j0 + j*16 + hi*4]);
            s[0][j][0] = mv.x>0.f ? s[0][j][0] : NEG_MAX;  s[1][j][0] = mv.x>0.f ? s[1][j][0] : NEG_MAX;
            s[0][j][1] = mv.y>0.f ? s[0][j][1] : NEG_MAX;  s[1][j][1] = mv.y>0.f ? s[1][j][1] : NEG_MAX;
            s[0][j][2] = mv.z>0.f ? s[0][j][2] : NEG_MAX;  s[1][j][2] = mv.z>0.f ? s[1][j][2] : NEG_MAX;
            s[0][j][3] = mv.w>0.f ? s[0][j][3] : NEG_MAX;  s[1][j][3] = mv.w>0.f ? s[1][j][3] : NEG_MAX;
        }

        // ---- online softmax with defer-max (exp2 domain, THR=8) ----
        #pragma unroll
        for (int qs=0; qs<2; qs++){
            float m0_ = fmaxf(fmaxf(s[qs][0][0], s[qs][0][1]), s[qs][0][2]);
            float m1_ = fmaxf(fmaxf(s[qs][0][3], s[qs][1][0]), s[qs][1][1]);
            float m2_ = fmaxf(fmaxf(s[qs][1][2], s[qs][1][3]), s[qs][2][0]);
            float m3_ = fmaxf(fmaxf(s[qs][2][1], s[qs][2][2]), s[qs][2][3]);
            float m4_ = fmaxf(fmaxf(s[qs][3][0], s[qs][3][1]), s[qs][3][2]);
            float mt = fmaxf(fmaxf(fmaxf(m0_,m1_),m2_), fmaxf(fmaxf(m3_,m4_), s[qs][3][3]));
            mt = fmaxf(mt, __shfl_xor(mt, 16));
            mt = fmaxf(mt, __shfl_xor(mt, 32));
            if (__any(mt > mrun[qs] + 8.f)){
                float mnew = fmaxf(mrun[qs], mt);
                float cc = __builtin_amdgcn_exp2f(mrun[qs] - mnew);
                lrun[qs] *= cc;
                mrun[qs] = mnew;
                #pragma unroll
                for (int r=0;r<4;r++){
                    float ccr = __shfl(cc, hi*4 + r);
                    #pragma unroll
                    for (int dt=0; dt<4; dt++) o[qs][dt][r] *= ccr;
                }
            }
            float p[4][4];
            #pragma unroll
            for (int j=0;j<4;j++)
                #pragma unroll
                for (int r=0;r<4;r++) p[j][r] = __builtin_amdgcn_exp2f(s[qs][j][r] - mrun[qs]);
            float r0 = (p[0][0]+p[0][1]) + (p[0][2]+p[0][3]);
            float r1 = (p[1][0]+p[1][1]) + (p[1][2]+p[1][3]);
            float r2 = (p[2][0]+p[2][1]) + (p[2][2]+p[2][3]);
            float r3 = (p[3][0]+p[3][1]) + (p[3][2]+p[3][3]);
            float rs = (r0+r1)+(r2+r3);
            rs += __shfl_xor(rs, 16);
            rs += __shfl_xor(rs, 32);
            lrun[qs] += rs;
            #pragma unroll
            for (int j=0;j<4;j++){
                uint2 wd;
                wd.x = (unsigned)f2bf(p[j][0]) | ((unsigned)f2bf(p[j][1])<<16);
                wd.y = (unsigned)f2bf(p[j][2]) | ((unsigned)f2bf(p[j][3])<<16);
                *(uint2*)(PsB + (qs*16+lo)*144 + ((j*32 + hi*8) ^ swzq)) = wd;
            }
        }

        // ---- P A-frags + O += P V ----
        bh8 ap[2][2];
        #pragma unroll
        for (int qs=0; qs<2; qs++){
            ap[qs][0] = *(const bh8*)(PsB + (qs*16+lo)*144 + ((hi*16) ^ swzq));
            ap[qs][1] = *(const bh8*)(PsB + (qs*16+lo)*144 + ((64 + hi*16) ^ swzq));
        }
        __builtin_amdgcn_s_setprio(1);
        #pragma unroll
        for (int dt=0; dt<4; dt++){
            int row = dt*16 + lo;
            int vswz = (row&7)<<4;
            bh8 bv0 = *(const bh8*)(VsB + row*128 + ((hi*16) ^ vswz));
            bh8 bv1 = *(const bh8*)(VsB + row*128 + ((64 + hi*16) ^ vswz));
            o[0][dt] = __builtin_amdgcn_mfma_f32_16x16x32_bf16(ap[0][0], bv0, o[0][dt], 0,0,0);
            o[0][dt] = __builtin_amdgcn_mfma_f32_16x16x32_bf16(ap[0][1], bv1, o[0][dt], 0,0,0);
            o[1][dt] = __builtin_amdgcn_mfma_f32_16x16x32_bf16(ap[1][0], bv0, o[1][dt], 0,0,0);
            o[1][dt] = __builtin_amdgcn_mfma_f32_16x16x32_bf16(ap[1][1], bv1, o[1][dt], 0,0,0);
        }
        __builtin_amdgcn_s_setprio(0);
        __builtin_amdgcn_s_barrier();              // all reads of cur done before next prefetch
    }
    #undef STAGE

    // ---- epilogue ----
    #pragma unroll
    for (int qs=0; qs<2; qs++){
        float inv = 1.f / lrun[qs];
        #pragma unroll
        for (int r=0;r<4;r++){
            float ivr = __shfl(inv, hi*4 + r);
            int l_ = q0 + w*32 + qs*16 + hi*4 + r;
            size_t base = ((size_t)b*NL + l_)*NDIM + h*NDH;
            #pragma unroll
            for (int dt=0; dt<4; dt++)
                ao[base + dt*16 + lo] = f2bf(o[qs][dt][r] * ivr);
        }
    }
}

extern "C" void kernel_launch(void* const* d_in, const int* in_sizes, int n_in,
                              void* d_out, int out_size, void* d_ws, size_t ws_size,
                              hipStream_t stream) {
    const float* x      = (const float*)d_in[0];
    const float* time_  = (const float*)d_in[1];
    const float* smask  = (const float*)d_in[2];
    const float* cycm   = (const float*)d_in[3];
    const float* gamma  = (const float*)d_in[4];
    const float* Wt     = (const float*)d_in[5];
    const float* bt     = (const float*)d_in[6];
    const float* Wq     = (const float*)d_in[7];
    const float* Wkv    = (const float*)d_in[8];
    const float* Wo     = (const float*)d_in[9];
    const float* rf     = (const float*)d_in[10];
    const int*   resi   = (const int*)d_in[11];
    const int*   chain  = (const int*)d_in[12];
    float* out = (float*)d_out;

    float*  ss     = (float*)d_ws;                   // 8192 f
    float*  cnts   = ss + 8192;                      // 16 f
    float2* cs     = (float2*)(cnts + 16);           // 131072 float2
    ushort* xc     = (ushort*)(cs + 131072);         // 4096*1024
    ushort* wqkv   = xc + 4194304;                   // 3072*1024
    ushort* wo     = wqkv + 3145728;                 // 1024*1024
    ushort* qbuf   = wo + 1048576;                   // [B,H,L,DH]
    ushort* kbuf   = qbuf + 4194304;
    ushort* vtb    = kbuf + 4194304;                 // [B,H,DH,L]
    ushort* aob    = vtb + 4194304;

    hipLaunchKernelGGL(k_pre1,   dim3(6152),   dim3(256), 0, stream,
                       time_, Wt, bt, ss, chain, cycm, cnts, Wq, Wkv, Wo, wqkv, wo);
    hipLaunchKernelGGL(k_pre2,   dim3(4608),   dim3(256), 0, stream,
                       resi, chain, cycm, rf, cnts, cs, x, smask, gamma, ss, xc);
    hipLaunchKernelGGL((k_mm<0>), dim3(24,32), dim3(256), 0, stream,
                       xc, wqkv, qbuf, kbuf, vtb, (float*)nullptr, (const float*)nullptr, (const float2*)cs);
    hipLaunchKernelGGL(k_fattn,  dim3(512),    dim3(256), 0, stream,
                       qbuf, kbuf, vtb, smask, aob);
    hipLaunchKernelGGL((k_mm<1>), dim3(8,32),  dim3(256), 0, stream,
                       aob, wo, (ushort*)nullptr, (ushort*)nullptr, (ushort*)nullptr, out, smask,
                       (const float2*)nullptr);
}